// Round 5
// baseline (267.311 us; speedup 1.0000x reference)
//
#include <hip/hip_runtime.h>
#include <math.h>

namespace {

constexpr int T  = 2048;
constexpr int HD = 64;
constexpr float EPS = 1.1920929e-07f;
// SCALE * log2(e), folded into q at proj_q write time -> attn softmax runs in exp2 domain
constexpr float PS = 0.125f * 1.44269504f;

// bf16 weight pool offsets (in elements)
constexpr int OFF_DQ  = 0;       // 512*64
constexpr int OFF_UQ  = 32768;   // 64*512
constexpr int OFF_DKV = 65536;   // 1024*64
constexpr int OFF_UKV = 131072;  // 128*1024
constexpr int OFF_QR  = 262144;  // 64*64
constexpr int OFF_KR  = 266240;  // 64*64
constexpr int OFF_O   = 270336;  // 64*64
constexpr int W_TOTAL = 274432;

typedef __attribute__((ext_vector_type(8))) short bf8v;  // 8 bf16 (4 VGPR)
typedef __attribute__((ext_vector_type(4))) float f4v;   // MFMA C/D

#define MFMA16(a, b, c) __builtin_amdgcn_mfma_f32_16x16x32_bf16((a), (b), (c), 0, 0, 0)

__device__ __forceinline__ short f2bf(float f) {
  union { float f; unsigned u; } v; v.f = f;
  unsigned r = v.u + 0x7FFFu + ((v.u >> 16) & 1u); // RNE
  return (short)(r >> 16);
}

__device__ __forceinline__ f4v z4() { f4v z = {0.f, 0.f, 0.f, 0.f}; return z; }

// XOR swizzles: spread row-strided b128 accesses across banks (m214 pattern)
__device__ __forceinline__ int swz128(int b) { return b ^ (((b >> 7) & 7) << 4); }
__device__ __forceinline__ int swz256(int b) { return b ^ (((b >> 8) & 7) << 4); }

__device__ __forceinline__ bf8v ldA128(const short* lds, int row, int k) {
  return *(const bf8v*)((const char*)lds + swz128(row * 128 + k * 2));
}

// stage a row-major 64x64 bf16 tile (src row stride = stride elems) into swizzled LDS
__device__ __forceinline__ void stage64x64(short* lds, const short* src, int stride, int tid) {
#pragma unroll
  for (int p = 0; p < 2; ++p) {
    int ci = tid + p * 256;
    int r = ci >> 3, c = (ci & 7) << 3;
    bf8v v = *(const bf8v*)(src + (size_t)r * stride + c);
    *(bf8v*)((char*)lds + swz128(ci * 16)) = v;
  }
}
__device__ __forceinline__ void stage128x64(short* lds, const short* src, int stride, int tid) {
#pragma unroll
  for (int p = 0; p < 4; ++p) {
    int ci = tid + p * 256;
    int r = ci >> 3, c = (ci & 7) << 3;
    bf8v v = *(const bf8v*)(src + (size_t)r * stride + c);
    *(bf8v*)((char*)lds + swz128(ci * 16)) = v;
  }
}

// scatter a 16x16 D-fragment (col=lane&15, row=(lane>>4)*4+r) as bf16 into LDS
__device__ __forceinline__ void scat128(short* lds, int row0, int lane, int nt, f4v v) {
  int col = nt * 16 + (lane & 15);
  int r0 = row0 + ((lane >> 4) << 2);
#pragma unroll
  for (int r = 0; r < 4; ++r)
    *(short*)((char*)lds + swz128((r0 + r) * 128 + col * 2)) = f2bf(v[r]);
}
__device__ __forceinline__ void scat256(short* lds, int row0, int lane, int col, f4v v) {
  int r0 = row0 + ((lane >> 4) << 2);
#pragma unroll
  for (int r = 0; r < 4; ++r)
    *(short*)((char*)lds + swz256((r0 + r) * 256 + col * 2)) = f2bf(v[r]);
}

// DPP 16-lane row reductions (quad_perm swaps + mirrors) — full-rate VALU
__device__ __forceinline__ float i2f(int i) { union { int i; float f; } u; u.i = i; return u.f; }
__device__ __forceinline__ int f2i(float f) { union { float f; int i; } u; u.f = f; return u.i; }
template <int C>
__device__ __forceinline__ float dppf(float x) {
  return i2f(__builtin_amdgcn_update_dpp(f2i(x), f2i(x), C, 0xF, 0xF, false));
}
__device__ __forceinline__ float rowmax16(float x) {
  x = fmaxf(x, dppf<0xB1>(x));   // quad_perm [1,0,3,2]
  x = fmaxf(x, dppf<0x4E>(x));   // quad_perm [2,3,0,1]
  x = fmaxf(x, dppf<0x141>(x));  // row_half_mirror
  x = fmaxf(x, dppf<0x140>(x));  // row_mirror
  return x;
}
__device__ __forceinline__ float rowsum16(float x) {
  x += dppf<0xB1>(x);
  x += dppf<0x4E>(x);
  x += dppf<0x141>(x);
  x += dppf<0x140>(x);
  return x;
}

// ---------------------------------------------------------------------------
// conversions
// ---------------------------------------------------------------------------
__global__ __launch_bounds__(256) void cvt_x_kernel(const float* __restrict__ x,
                                                    short* __restrict__ xb) {
  int i = (blockIdx.x * 256 + threadIdx.x) * 4; // over x linear (B,T,D)
  float4 v = *(const float4*)(x + i);
  int d = i & 1023, t = (i >> 10) & 2047, b = i >> 21;
  int h = d >> 6, dd = d & 63;
  short4 o;
  o.x = f2bf(v.x); o.y = f2bf(v.y); o.z = f2bf(v.z); o.w = f2bf(v.w);
  *(short4*)(xb + ((((size_t)b * 16 + h) * T + t) * 64 + dd)) = o;
}

__global__ __launch_bounds__(256) void cvt_w_kernel(
    const float* __restrict__ W_DQ, const float* __restrict__ W_UQ,
    const float* __restrict__ W_DKV, const float* __restrict__ W_UKV,
    const float* __restrict__ W_QR, const float* __restrict__ W_KR,
    const float* __restrict__ W_O, short* __restrict__ wb) {
  int i = blockIdx.x * 256 + threadIdx.x;
  const float* src; int off;
  if      (i < 32768)  { src = W_DQ;  off = 0; }
  else if (i < 65536)  { src = W_UQ;  off = 32768; }
  else if (i < 131072) { src = W_DKV; off = 65536; }
  else if (i < 262144) { src = W_UKV; off = 131072; }
  else if (i < 266240) { src = W_QR;  off = 262144; }
  else if (i < 270336) { src = W_KR;  off = 266240; }
  else                 { src = W_O;   off = 270336; }
  wb[i] = f2bf(src[i - off]);
}

// ---------------------------------------------------------------------------
// proj_q: q[bh][t][0:64]=PS*rmsnorm((xh WDQ^T) WUQ^T)*qnw ; [64:128]= that @ WQR^T
// PS = SCALE*log2e folded in via w4 ONLY (inv must NOT carry PS — round-4 bug
// was inv's 1/PS cancelling w4's PS, leaving q unscaled).
// ---------------------------------------------------------------------------
__global__ __launch_bounds__(256) void proj_q_mfma(
    const short* __restrict__ xb, const short* __restrict__ wb,
    const float* __restrict__ qnw, short* __restrict__ qb) {
  __shared__ __attribute__((aligned(16))) short Xs[64 * 64];
  __shared__ __attribute__((aligned(16))) short Wd[64 * 64];
  __shared__ __attribute__((aligned(16))) short Wu[64 * 64];
  __shared__ __attribute__((aligned(16))) short Cs[64 * 64];
  __shared__ __attribute__((aligned(16))) short Qr[64 * 64];

  const int tid = threadIdx.x, lane = tid & 63, w = tid >> 6;
  const int bh = blockIdx.y, t0 = blockIdx.x * 64;
  const int arow = w * 16 + (lane & 15);
  const int koff = (lane >> 4) << 3;

  stage64x64(Xs, xb + ((size_t)bh * T + t0) * 64, 64, tid);

  f4v acc[4];
#pragma unroll
  for (int nt = 0; nt < 4; ++nt) acc[nt] = z4();

  for (int lc = 0; lc < 8; ++lc) {
    const int l0 = lc * 64;
    __syncthreads();
    stage64x64(Wd, wb + OFF_DQ + (size_t)l0 * 64, 64, tid);
    stage64x64(Wu, wb + OFF_UQ + l0, 512, tid);
    __syncthreads();
    f4v cc[4];
#pragma unroll
    for (int nt = 0; nt < 4; ++nt) cc[nt] = z4();
#pragma unroll
    for (int ks = 0; ks < 2; ++ks) {
      bf8v a = ldA128(Xs, arow, ks * 32 + koff);
#pragma unroll
      for (int nt = 0; nt < 4; ++nt) {
        bf8v b = ldA128(Wd, nt * 16 + (lane & 15), ks * 32 + koff);
        cc[nt] = MFMA16(a, b, cc[nt]);
      }
    }
#pragma unroll
    for (int nt = 0; nt < 4; ++nt) scat128(Cs, w * 16, lane, nt, cc[nt]);
#pragma unroll
    for (int ks = 0; ks < 2; ++ks) {
      bf8v a = ldA128(Cs, arow, ks * 32 + koff);
#pragma unroll
      for (int nt = 0; nt < 4; ++nt) {
        bf8v b = ldA128(Wu, nt * 16 + (lane & 15), ks * 32 + koff);
        acc[nt] = MFMA16(a, b, acc[nt]);
      }
    }
  }

  float w4[4];
#pragma unroll
  for (int nt = 0; nt < 4; ++nt) w4[nt] = qnw[nt * 16 + (lane & 15)] * PS;
  f4v qn[4];
#pragma unroll
  for (int r = 0; r < 4; ++r) {
    float ss = 0.f;
#pragma unroll
    for (int nt = 0; nt < 4; ++nt) ss += acc[nt][r] * acc[nt][r];
    ss += __shfl_xor(ss, 1, 16); ss += __shfl_xor(ss, 2, 16);
    ss += __shfl_xor(ss, 4, 16); ss += __shfl_xor(ss, 8, 16);
    float inv = rsqrtf(ss * (1.f / 64.f) + EPS); // reference rms of q_c; PS lives in w4
#pragma unroll
    for (int nt = 0; nt < 4; ++nt) qn[nt][r] = acc[nt][r] * inv * w4[nt];
  }

  __syncthreads();
#pragma unroll
  for (int nt = 0; nt < 4; ++nt) scat128(Cs, w * 16, lane, nt, qn[nt]);
  stage64x64(Wd, wb + OFF_QR, 64, tid);
  __syncthreads();

  f4v qr[4];
#pragma unroll
  for (int nt = 0; nt < 4; ++nt) qr[nt] = z4();
#pragma unroll
  for (int ks = 0; ks < 2; ++ks) {
    bf8v a = ldA128(Cs, arow, ks * 32 + koff);
#pragma unroll
    for (int nt = 0; nt < 4; ++nt) {
      bf8v b = ldA128(Wd, nt * 16 + (lane & 15), ks * 32 + koff);
      qr[nt] = MFMA16(a, b, qr[nt]);
    }
  }
#pragma unroll
  for (int nt = 0; nt < 4; ++nt) scat128(Qr, w * 16, lane, nt, qr[nt]);
  __syncthreads();

  short* qdst = qb + ((size_t)bh * T + t0) * 128;
#pragma unroll
  for (int p = 0; p < 2; ++p) {
    int ci = tid + p * 256;
    int r = ci >> 3, c = (ci & 7) << 3;
    *(bf8v*)(qdst + (size_t)r * 128 + c) =
        *(const bf8v*)((const char*)Cs + swz128(ci * 16));
    *(bf8v*)(qdst + (size_t)r * 128 + 64 + c) =
        *(const bf8v*)((const char*)Qr + swz128(ci * 16));
  }
}

// ---------------------------------------------------------------------------
// proj_kv (unchanged)
// ---------------------------------------------------------------------------
__global__ __launch_bounds__(256) void proj_kv_mfma(
    const short* __restrict__ xb, const short* __restrict__ wb,
    const float* __restrict__ knw, short* __restrict__ kb, short* __restrict__ vtg) {
  __shared__ __attribute__((aligned(16))) short Xs[64 * 64];
  __shared__ __attribute__((aligned(16))) short Wd[64 * 64];
  __shared__ __attribute__((aligned(16))) short Cs[64 * 64];
  __shared__ __attribute__((aligned(16))) short Wu[128 * 64];
  __shared__ __attribute__((aligned(16))) short Ko[64 * 128];
  __shared__ __attribute__((aligned(16))) short Vt[64 * 64];

  const int tid = threadIdx.x, lane = tid & 63, w = tid >> 6;
  const int bh = blockIdx.y, t0 = blockIdx.x * 64;
  const int arow = w * 16 + (lane & 15);
  const int koff = (lane >> 4) << 3;

  stage64x64(Xs, xb + ((size_t)bh * T + t0) * 64, 64, tid);

  f4v acc[8];
#pragma unroll
  for (int nt = 0; nt < 8; ++nt) acc[nt] = z4();

  for (int lc = 0; lc < 16; ++lc) {
    const int l0 = lc * 64;
    __syncthreads();
    stage64x64(Wd, wb + OFF_DKV + (size_t)l0 * 64, 64, tid);
    stage128x64(Wu, wb + OFF_UKV + l0, 1024, tid);
    __syncthreads();
    f4v cc[4];
#pragma unroll
    for (int nt = 0; nt < 4; ++nt) cc[nt] = z4();
#pragma unroll
    for (int ks = 0; ks < 2; ++ks) {
      bf8v a = ldA128(Xs, arow, ks * 32 + koff);
#pragma unroll
      for (int nt = 0; nt < 4; ++nt) {
        bf8v b = ldA128(Wd, nt * 16 + (lane & 15), ks * 32 + koff);
        cc[nt] = MFMA16(a, b, cc[nt]);
      }
    }
#pragma unroll
    for (int nt = 0; nt < 4; ++nt) scat128(Cs, w * 16, lane, nt, cc[nt]);
#pragma unroll
    for (int ks = 0; ks < 2; ++ks) {
      bf8v a = ldA128(Cs, arow, ks * 32 + koff);
#pragma unroll
      for (int nt = 0; nt < 8; ++nt) {
        bf8v b = ldA128(Wu, nt * 16 + (lane & 15), ks * 32 + koff);
        acc[nt] = MFMA16(a, b, acc[nt]);
      }
    }
  }

  float w4[4];
#pragma unroll
  for (int nt = 0; nt < 4; ++nt) w4[nt] = knw[nt * 16 + (lane & 15)];
#pragma unroll
  for (int r = 0; r < 4; ++r) {
    float ss = 0.f;
#pragma unroll
    for (int nt = 0; nt < 4; ++nt) ss += acc[nt][r] * acc[nt][r];
    ss += __shfl_xor(ss, 1, 16); ss += __shfl_xor(ss, 2, 16);
    ss += __shfl_xor(ss, 4, 16); ss += __shfl_xor(ss, 8, 16);
    float inv = rsqrtf(ss * (1.f / 64.f) + EPS);
#pragma unroll
    for (int nt = 0; nt < 4; ++nt) acc[nt][r] *= inv * w4[nt];
  }
#pragma unroll
  for (int nt = 0; nt < 4; ++nt) scat256(Ko, w * 16, lane, nt * 16 + (lane & 15), acc[nt]);
#pragma unroll
  for (int nt = 0; nt < 4; ++nt) {
    int d = nt * 16 + (lane & 15);
    int tl0 = w * 16 + ((lane >> 4) << 2);
#pragma unroll
    for (int r = 0; r < 4; ++r)
      *(short*)((char*)Vt + swz128(d * 128 + (tl0 + r) * 2)) = f2bf(acc[4 + nt][r]);
  }

  __syncthreads();
  stage64x64(Wd, wb + OFF_KR, 64, tid);
  __syncthreads();
  f4v kr[4];
#pragma unroll
  for (int nt = 0; nt < 4; ++nt) kr[nt] = z4();
#pragma unroll
  for (int ks = 0; ks < 2; ++ks) {
    bf8v a = ldA128(Xs, arow, ks * 32 + koff);
#pragma unroll
    for (int nt = 0; nt < 4; ++nt) {
      bf8v b = ldA128(Wd, nt * 16 + (lane & 15), ks * 32 + koff);
      kr[nt] = MFMA16(a, b, kr[nt]);
    }
  }
#pragma unroll
  for (int nt = 0; nt < 4; ++nt) scat256(Ko, w * 16, lane, 64 + nt * 16 + (lane & 15), kr[nt]);
  __syncthreads();

  short* kdst = kb + ((size_t)bh * T + t0) * 128;
#pragma unroll
  for (int p = 0; p < 4; ++p) {
    int ci = tid + p * 256;
    int r = ci >> 4, c = (ci & 15) << 3;
    *(bf8v*)(kdst + (size_t)r * 128 + c) =
        *(const bf8v*)((const char*)Ko + swz256(ci * 16));
  }
#pragma unroll
  for (int p = 0; p < 2; ++p) {
    int ci = tid + p * 256;
    int d = ci >> 3, c = (ci & 7) << 3;
    *(bf8v*)(vtg + ((size_t)bh * 64 + d) * T + t0 + c) =
        *(const bf8v*)((const char*)Vt + swz128(ci * 16));
  }
}

// ---------------------------------------------------------------------------
// attn v4b: barrier-free. K B-fragments read directly from global (XCD-L2-
// resident via bh clustering); LDS holds only the wave-private P round-trip.
// exp2-domain softmax (scale pre-folded into q), diag-only masking, defer-max.
// grid (16, 32) paired q-tiles, block 256.
// ---------------------------------------------------------------------------
__global__ __launch_bounds__(256) void attn_mfma(
    const short* __restrict__ qb, const short* __restrict__ kb,
    const short* __restrict__ vtg, const short* __restrict__ wb,
    float* __restrict__ out) {
  __shared__ __attribute__((aligned(16))) short Ps[64 * 64]; // swz128, wave-banded

  const int tid = threadIdx.x, lane = tid & 63, w = tid >> 6;
  const int lin = blockIdx.y * 16 + blockIdx.x; // [0,512)
  const int xcd = lin & 7, slot = lin >> 3;     // slot [0,64)
  const int bh = xcd + 8 * (slot >> 4);         // 4 bh per XCD -> KV L2-resident
  const int px = slot & 15;
  const int qt_pair[2] = {px, 31 - px};

  const int b = bh >> 4, h = bh & 15;
  const int koff = (lane >> 4) << 3;
  const int c16 = lane & 15;

  const short* kbh = kb + (size_t)bh * T * 128;
  const short* vbh = vtg + (size_t)bh * 64 * T;

  for (int seg = 0; seg < 2; ++seg) {
    const int qt = qt_pair[seg];
    const int t0 = qt * 64;
    const int lrow = w * 16 + ((lane >> 4) << 2);

    bf8v aq[4];
    {
      const short* qsrc = qb + ((size_t)bh * T + t0 + w * 16 + c16) * 128;
#pragma unroll
      for (int ks = 0; ks < 4; ++ks) aq[ks] = *(const bf8v*)(qsrc + ks * 32 + koff);
    }

    f4v ctx[4];
    float m[4], l[4];
#pragma unroll
    for (int nt = 0; nt < 4; ++nt) ctx[nt] = z4();
#pragma unroll
    for (int r = 0; r < 4; ++r) { m[r] = -INFINITY; l[r] = 0.f; }

    for (int jt = 0; jt <= qt; ++jt) {
      const int j0 = jt * 64;
      const bool diag = (jt == qt);

      // V fragments (latency hides under QK below; no barriers anywhere)
      bf8v vb[2][4];
#pragma unroll
      for (int ks = 0; ks < 2; ++ks)
#pragma unroll
        for (int nt = 0; nt < 4; ++nt)
          vb[ks][nt] = *(const bf8v*)(vbh + (size_t)(nt * 16 + c16) * T +
                                      j0 + ks * 32 + koff);

      // QK^T: K B-fragments straight from global/L2 (already exp2-scaled via q)
      f4v s[4];
#pragma unroll
      for (int nt = 0; nt < 4; ++nt) s[nt] = z4();
#pragma unroll
      for (int ks = 0; ks < 4; ++ks) {
#pragma unroll
        for (int nt = 0; nt < 4; ++nt) {
          bf8v bk = *(const bf8v*)(kbh + (size_t)(j0 + nt * 16 + c16) * 128 +
                                   ks * 32 + koff);
          s[nt] = MFMA16(aq[ks], bk, s[nt]);
        }
      }

      if (diag) { // causal mask only on the diagonal tile
#pragma unroll
        for (int r = 0; r < 4; ++r) {
          const int grow = t0 + lrow + r;
#pragma unroll
          for (int nt = 0; nt < 4; ++nt)
            if (j0 + nt * 16 + c16 > grow) s[nt][r] = -INFINITY;
        }
      }

      // online softmax, exp2 domain, defer-max (THR=8 -> p bounded by 2^8)
      float mx4[4], need = -1e30f;
#pragma unroll
      for (int r = 0; r < 4; ++r) {
        float mx = rowmax16(fmaxf(fmaxf(s[0][r], s[1][r]), fmaxf(s[2][r], s[3][r])));
        mx4[r] = mx;
        need = fmaxf(need, mx - m[r]);
      }
      if (__any(need > 8.f)) {
#pragma unroll
        for (int r = 0; r < 4; ++r) {
          const float mn  = fmaxf(m[r], mx4[r]);
          const float scl = __builtin_amdgcn_exp2f(m[r] - mn);
          l[r] *= scl;
#pragma unroll
          for (int nt = 0; nt < 4; ++nt) ctx[nt][r] *= scl;
          m[r] = mn;
        }
      }
#pragma unroll
      for (int r = 0; r < 4; ++r) {
        float rs = 0.f, p4[4];
#pragma unroll
        for (int nt = 0; nt < 4; ++nt) {
          p4[nt] = __builtin_amdgcn_exp2f(s[nt][r] - m[r]);
          rs += p4[nt];
        }
        l[r] += rowsum16(rs);
#pragma unroll
        for (int nt = 0; nt < 4; ++nt)
          *(short*)((char*)Ps + swz128((lrow + r) * 128 + (nt * 16 + c16) * 2)) =
              f2bf(p4[nt]);
      }

      // PV: P from wave-private LDS band, V from regs
#pragma unroll
      for (int ks = 0; ks < 2; ++ks) {
        bf8v pa = ldA128(Ps, w * 16 + c16, ks * 32 + koff);
#pragma unroll
        for (int nt = 0; nt < 4; ++nt) ctx[nt] = MFMA16(pa, vb[ks][nt], ctx[nt]);
      }
    }

    // epilogue: ctx/l -> Ps (wave band), out = ctx @ W_O^T (W_O frags from global)
    f4v cn[4];
#pragma unroll
    for (int nt = 0; nt < 4; ++nt) {
#pragma unroll
      for (int r = 0; r < 4; ++r) cn[nt][r] = ctx[nt][r] / l[r];
    }
#pragma unroll
    for (int nt = 0; nt < 4; ++nt) scat128(Ps, w * 16, lane, nt, cn[nt]);

    f4v o[4];
#pragma unroll
    for (int nt = 0; nt < 4; ++nt) o[nt] = z4();
#pragma unroll
    for (int ks = 0; ks < 2; ++ks) {
      bf8v pa = ldA128(Ps, w * 16 + c16, ks * 32 + koff);
#pragma unroll
      for (int nt = 0; nt < 4; ++nt) {
        bf8v bw = *(const bf8v*)(wb + OFF_O + (size_t)(nt * 16 + c16) * 64 +
                                 ks * 32 + koff);
        o[nt] = MFMA16(pa, bw, o[nt]);
      }
    }

    float* obase = out + (size_t)b * T * 1024 + h * 64;
#pragma unroll
    for (int nt = 0; nt < 4; ++nt) {
#pragma unroll
      for (int r = 0; r < 4; ++r)
        obase[(size_t)(t0 + lrow + r) * 1024 + nt * 16 + c16] = o[nt][r];
    }
  }
}

} // namespace

extern "C" void kernel_launch(void* const* d_in, const int* in_sizes, int n_in,
                              void* d_out, int out_size, void* d_ws, size_t ws_size,
                              hipStream_t stream) {
  (void)in_sizes; (void)n_in; (void)out_size; (void)ws_size;
  const float* x     = (const float*)d_in[0];
  const float* W_DQ  = (const float*)d_in[1];
  const float* W_UQ  = (const float*)d_in[2];
  const float* W_DKV = (const float*)d_in[3];
  const float* W_UKV = (const float*)d_in[4];
  const float* W_QR  = (const float*)d_in[5];
  const float* W_KR  = (const float*)d_in[6];
  const float* W_O   = (const float*)d_in[7];
  const float* qnw   = (const float*)d_in[8];
  const float* knw   = (const float*)d_in[9];
  float* out = (float*)d_out;

  short* ws = (short*)d_ws;
  short* xb  = ws;                          // 4,194,304
  short* qb  = ws + (size_t)4194304;        // 8,388,608
  short* kb  = ws + (size_t)12582912;       // 8,388,608
  short* vtg = ws + (size_t)20971520;       // 4,194,304
  short* wb  = ws + (size_t)25165824;       // 274,432

  cvt_x_kernel<<<4096, 256, 0, stream>>>(x, xb);
  cvt_w_kernel<<<W_TOTAL / 256, 256, 0, stream>>>(W_DQ, W_UQ, W_DKV, W_UKV,
                                                  W_QR, W_KR, W_O, wb);
  dim3 grid(T / 64, 32);
  proj_q_mfma<<<grid, 256, 0, stream>>>(xb, wb, qnw, qb);
  proj_kv_mfma<<<grid, 256, 0, stream>>>(xb, wb, knw, kb, vtg);
  dim3 agrid(16, 32); // paired q-tiles, uniform work
  attn_mfma<<<agrid, 256, 0, stream>>>(qb, kb, vtg, wb, out);
}

// Round 6
// 178.783 us; speedup vs baseline: 1.4952x; 1.4952x over previous
//
#include <hip/hip_runtime.h>
#include <math.h>

namespace {

constexpr int T  = 2048;
constexpr int HD = 64;
constexpr float EPS = 1.1920929e-07f;
// SCALE * log2(e), folded into q at proj_q write time -> attn softmax runs in exp2 domain
constexpr float PS = 0.125f * 1.44269504f;

// bf16 weight pool offsets (in elements)
constexpr int OFF_DQ  = 0;       // 512*64
constexpr int OFF_UQ  = 32768;   // 64*512
constexpr int OFF_DKV = 65536;   // 1024*64
constexpr int OFF_UKV = 131072;  // 128*1024
constexpr int OFF_QR  = 262144;  // 64*64
constexpr int OFF_KR  = 266240;  // 64*64
constexpr int OFF_O   = 270336;  // 64*64
constexpr int W_TOTAL = 274432;

typedef __attribute__((ext_vector_type(8))) short bf8v;  // 8 bf16 (4 VGPR)
typedef __attribute__((ext_vector_type(4))) float f4v;   // MFMA C/D

#define MFMA16(a, b, c) __builtin_amdgcn_mfma_f32_16x16x32_bf16((a), (b), (c), 0, 0, 0)

__device__ __forceinline__ short f2bf(float f) {
  union { float f; unsigned u; } v; v.f = f;
  unsigned r = v.u + 0x7FFFu + ((v.u >> 16) & 1u); // RNE
  return (short)(r >> 16);
}

__device__ __forceinline__ f4v z4() { f4v z = {0.f, 0.f, 0.f, 0.f}; return z; }

// XOR swizzles: spread row-strided b128 accesses across banks (m214 pattern)
__device__ __forceinline__ int swz128(int b) { return b ^ (((b >> 7) & 7) << 4); }
__device__ __forceinline__ int swz256(int b) { return b ^ (((b >> 8) & 7) << 4); }

__device__ __forceinline__ bf8v ldA128(const short* lds, int row, int k) {
  return *(const bf8v*)((const char*)lds + swz128(row * 128 + k * 2));
}
__device__ __forceinline__ bf8v ldA256(const short* lds, int row, int k) {
  return *(const bf8v*)((const char*)lds + swz256(row * 256 + k * 2));
}

// stage a row-major 64x64 bf16 tile (src row stride = stride elems) into swizzled LDS
__device__ __forceinline__ void stage64x64(short* lds, const short* src, int stride, int tid) {
#pragma unroll
  for (int p = 0; p < 2; ++p) {
    int ci = tid + p * 256;
    int r = ci >> 3, c = (ci & 7) << 3;
    bf8v v = *(const bf8v*)(src + (size_t)r * stride + c);
    *(bf8v*)((char*)lds + swz128(ci * 16)) = v;
  }
}
__device__ __forceinline__ void stage128x64(short* lds, const short* src, int stride, int tid) {
#pragma unroll
  for (int p = 0; p < 4; ++p) {
    int ci = tid + p * 256;
    int r = ci >> 3, c = (ci & 7) << 3;
    bf8v v = *(const bf8v*)(src + (size_t)r * stride + c);
    *(bf8v*)((char*)lds + swz128(ci * 16)) = v;
  }
}

// scatter a 16x16 D-fragment (col=lane&15, row=(lane>>4)*4+r) as bf16 into LDS
__device__ __forceinline__ void scat128(short* lds, int row0, int lane, int nt, f4v v) {
  int col = nt * 16 + (lane & 15);
  int r0 = row0 + ((lane >> 4) << 2);
#pragma unroll
  for (int r = 0; r < 4; ++r)
    *(short*)((char*)lds + swz128((r0 + r) * 128 + col * 2)) = f2bf(v[r]);
}
__device__ __forceinline__ void scat256(short* lds, int row0, int lane, int col, f4v v) {
  int r0 = row0 + ((lane >> 4) << 2);
#pragma unroll
  for (int r = 0; r < 4; ++r)
    *(short*)((char*)lds + swz256((r0 + r) * 256 + col * 2)) = f2bf(v[r]);
}

// async global->LDS, 16B per lane; LDS dest wave-uniform base + lane*16
__device__ __forceinline__ void gload_lds16(const void* g, void* l) {
  __builtin_amdgcn_global_load_lds(
      (const __attribute__((address_space(1))) void*)g,
      (__attribute__((address_space(3))) void*)l, 16, 0, 0);
}

// DPP 16-lane row reductions (quad_perm swaps + mirrors) — full-rate VALU
__device__ __forceinline__ float i2f(int i) { union { int i; float f; } u; u.i = i; return u.f; }
__device__ __forceinline__ int f2i(float f) { union { float f; int i; } u; u.f = f; return u.i; }
template <int C>
__device__ __forceinline__ float dppf(float x) {
  return i2f(__builtin_amdgcn_update_dpp(f2i(x), f2i(x), C, 0xF, 0xF, false));
}
__device__ __forceinline__ float rowmax16(float x) {
  x = fmaxf(x, dppf<0xB1>(x));   // quad_perm [1,0,3,2]
  x = fmaxf(x, dppf<0x4E>(x));   // quad_perm [2,3,0,1]
  x = fmaxf(x, dppf<0x141>(x));  // row_half_mirror
  x = fmaxf(x, dppf<0x140>(x));  // row_mirror
  return x;
}
__device__ __forceinline__ float rowsum16(float x) {
  x += dppf<0xB1>(x);
  x += dppf<0x4E>(x);
  x += dppf<0x141>(x);
  x += dppf<0x140>(x);
  return x;
}

// ---------------------------------------------------------------------------
// conversions
// ---------------------------------------------------------------------------
__global__ __launch_bounds__(256) void cvt_x_kernel(const float* __restrict__ x,
                                                    short* __restrict__ xb) {
  int i = (blockIdx.x * 256 + threadIdx.x) * 4; // over x linear (B,T,D)
  float4 v = *(const float4*)(x + i);
  int d = i & 1023, t = (i >> 10) & 2047, b = i >> 21;
  int h = d >> 6, dd = d & 63;
  short4 o;
  o.x = f2bf(v.x); o.y = f2bf(v.y); o.z = f2bf(v.z); o.w = f2bf(v.w);
  *(short4*)(xb + ((((size_t)b * 16 + h) * T + t) * 64 + dd)) = o;
}

__global__ __launch_bounds__(256) void cvt_w_kernel(
    const float* __restrict__ W_DQ, const float* __restrict__ W_UQ,
    const float* __restrict__ W_DKV, const float* __restrict__ W_UKV,
    const float* __restrict__ W_QR, const float* __restrict__ W_KR,
    const float* __restrict__ W_O, short* __restrict__ wb) {
  int i = blockIdx.x * 256 + threadIdx.x;
  const float* src; int off;
  if      (i < 32768)  { src = W_DQ;  off = 0; }
  else if (i < 65536)  { src = W_UQ;  off = 32768; }
  else if (i < 131072) { src = W_DKV; off = 65536; }
  else if (i < 262144) { src = W_UKV; off = 131072; }
  else if (i < 266240) { src = W_QR;  off = 262144; }
  else if (i < 270336) { src = W_KR;  off = 266240; }
  else                 { src = W_O;   off = 270336; }
  wb[i] = f2bf(src[i - off]);
}

// ---------------------------------------------------------------------------
// proj_q: q[bh][t][0:64]=PS*rmsnorm((xh WDQ^T) WUQ^T)*qnw ; [64:128]= that @ WQR^T
// PS folded via w4 ONLY (inv must NOT carry PS).
// ---------------------------------------------------------------------------
__global__ __launch_bounds__(256) void proj_q_mfma(
    const short* __restrict__ xb, const short* __restrict__ wb,
    const float* __restrict__ qnw, short* __restrict__ qb) {
  __shared__ __attribute__((aligned(16))) short Xs[64 * 64];
  __shared__ __attribute__((aligned(16))) short Wd[64 * 64];
  __shared__ __attribute__((aligned(16))) short Wu[64 * 64];
  __shared__ __attribute__((aligned(16))) short Cs[64 * 64];
  __shared__ __attribute__((aligned(16))) short Qr[64 * 64];

  const int tid = threadIdx.x, lane = tid & 63, w = tid >> 6;
  const int bh = blockIdx.y, t0 = blockIdx.x * 64;
  const int arow = w * 16 + (lane & 15);
  const int koff = (lane >> 4) << 3;

  stage64x64(Xs, xb + ((size_t)bh * T + t0) * 64, 64, tid);

  f4v acc[4];
#pragma unroll
  for (int nt = 0; nt < 4; ++nt) acc[nt] = z4();

  for (int lc = 0; lc < 8; ++lc) {
    const int l0 = lc * 64;
    __syncthreads();
    stage64x64(Wd, wb + OFF_DQ + (size_t)l0 * 64, 64, tid);
    stage64x64(Wu, wb + OFF_UQ + l0, 512, tid);
    __syncthreads();
    f4v cc[4];
#pragma unroll
    for (int nt = 0; nt < 4; ++nt) cc[nt] = z4();
#pragma unroll
    for (int ks = 0; ks < 2; ++ks) {
      bf8v a = ldA128(Xs, arow, ks * 32 + koff);
#pragma unroll
      for (int nt = 0; nt < 4; ++nt) {
        bf8v b = ldA128(Wd, nt * 16 + (lane & 15), ks * 32 + koff);
        cc[nt] = MFMA16(a, b, cc[nt]);
      }
    }
#pragma unroll
    for (int nt = 0; nt < 4; ++nt) scat128(Cs, w * 16, lane, nt, cc[nt]);
#pragma unroll
    for (int ks = 0; ks < 2; ++ks) {
      bf8v a = ldA128(Cs, arow, ks * 32 + koff);
#pragma unroll
      for (int nt = 0; nt < 4; ++nt) {
        bf8v b = ldA128(Wu, nt * 16 + (lane & 15), ks * 32 + koff);
        acc[nt] = MFMA16(a, b, acc[nt]);
      }
    }
  }

  float w4[4];
#pragma unroll
  for (int nt = 0; nt < 4; ++nt) w4[nt] = qnw[nt * 16 + (lane & 15)] * PS;
  f4v qn[4];
#pragma unroll
  for (int r = 0; r < 4; ++r) {
    float ss = 0.f;
#pragma unroll
    for (int nt = 0; nt < 4; ++nt) ss += acc[nt][r] * acc[nt][r];
    ss += __shfl_xor(ss, 1, 16); ss += __shfl_xor(ss, 2, 16);
    ss += __shfl_xor(ss, 4, 16); ss += __shfl_xor(ss, 8, 16);
    float inv = rsqrtf(ss * (1.f / 64.f) + EPS); // reference rms; PS lives in w4
#pragma unroll
    for (int nt = 0; nt < 4; ++nt) qn[nt][r] = acc[nt][r] * inv * w4[nt];
  }

  __syncthreads();
#pragma unroll
  for (int nt = 0; nt < 4; ++nt) scat128(Cs, w * 16, lane, nt, qn[nt]);
  stage64x64(Wd, wb + OFF_QR, 64, tid);
  __syncthreads();

  f4v qr[4];
#pragma unroll
  for (int nt = 0; nt < 4; ++nt) qr[nt] = z4();
#pragma unroll
  for (int ks = 0; ks < 2; ++ks) {
    bf8v a = ldA128(Cs, arow, ks * 32 + koff);
#pragma unroll
    for (int nt = 0; nt < 4; ++nt) {
      bf8v b = ldA128(Wd, nt * 16 + (lane & 15), ks * 32 + koff);
      qr[nt] = MFMA16(a, b, qr[nt]);
    }
  }
#pragma unroll
  for (int nt = 0; nt < 4; ++nt) scat128(Qr, w * 16, lane, nt, qr[nt]);
  __syncthreads();

  short* qdst = qb + ((size_t)bh * T + t0) * 128;
#pragma unroll
  for (int p = 0; p < 2; ++p) {
    int ci = tid + p * 256;
    int r = ci >> 3, c = (ci & 7) << 3;
    *(bf8v*)(qdst + (size_t)r * 128 + c) =
        *(const bf8v*)((const char*)Cs + swz128(ci * 16));
    *(bf8v*)(qdst + (size_t)r * 128 + 64 + c) =
        *(const bf8v*)((const char*)Qr + swz128(ci * 16));
  }
}

// ---------------------------------------------------------------------------
// proj_kv (unchanged)
// ---------------------------------------------------------------------------
__global__ __launch_bounds__(256) void proj_kv_mfma(
    const short* __restrict__ xb, const short* __restrict__ wb,
    const float* __restrict__ knw, short* __restrict__ kb, short* __restrict__ vtg) {
  __shared__ __attribute__((aligned(16))) short Xs[64 * 64];
  __shared__ __attribute__((aligned(16))) short Wd[64 * 64];
  __shared__ __attribute__((aligned(16))) short Cs[64 * 64];
  __shared__ __attribute__((aligned(16))) short Wu[128 * 64];
  __shared__ __attribute__((aligned(16))) short Ko[64 * 128];
  __shared__ __attribute__((aligned(16))) short Vt[64 * 64];

  const int tid = threadIdx.x, lane = tid & 63, w = tid >> 6;
  const int bh = blockIdx.y, t0 = blockIdx.x * 64;
  const int arow = w * 16 + (lane & 15);
  const int koff = (lane >> 4) << 3;

  stage64x64(Xs, xb + ((size_t)bh * T + t0) * 64, 64, tid);

  f4v acc[8];
#pragma unroll
  for (int nt = 0; nt < 8; ++nt) acc[nt] = z4();

  for (int lc = 0; lc < 16; ++lc) {
    const int l0 = lc * 64;
    __syncthreads();
    stage64x64(Wd, wb + OFF_DKV + (size_t)l0 * 64, 64, tid);
    stage128x64(Wu, wb + OFF_UKV + l0, 1024, tid);
    __syncthreads();
    f4v cc[4];
#pragma unroll
    for (int nt = 0; nt < 4; ++nt) cc[nt] = z4();
#pragma unroll
    for (int ks = 0; ks < 2; ++ks) {
      bf8v a = ldA128(Xs, arow, ks * 32 + koff);
#pragma unroll
      for (int nt = 0; nt < 4; ++nt) {
        bf8v b = ldA128(Wd, nt * 16 + (lane & 15), ks * 32 + koff);
        cc[nt] = MFMA16(a, b, cc[nt]);
      }
    }
#pragma unroll
    for (int nt = 0; nt < 4; ++nt) scat128(Cs, w * 16, lane, nt, cc[nt]);
#pragma unroll
    for (int ks = 0; ks < 2; ++ks) {
      bf8v a = ldA128(Cs, arow, ks * 32 + koff);
#pragma unroll
      for (int nt = 0; nt < 8; ++nt) {
        bf8v b = ldA128(Wu, nt * 16 + (lane & 15), ks * 32 + koff);
        acc[nt] = MFMA16(a, b, acc[nt]);
      }
    }
  }

  float w4[4];
#pragma unroll
  for (int nt = 0; nt < 4; ++nt) w4[nt] = knw[nt * 16 + (lane & 15)];
#pragma unroll
  for (int r = 0; r < 4; ++r) {
    float ss = 0.f;
#pragma unroll
    for (int nt = 0; nt < 4; ++nt) ss += acc[nt][r] * acc[nt][r];
    ss += __shfl_xor(ss, 1, 16); ss += __shfl_xor(ss, 2, 16);
    ss += __shfl_xor(ss, 4, 16); ss += __shfl_xor(ss, 8, 16);
    float inv = rsqrtf(ss * (1.f / 64.f) + EPS);
#pragma unroll
    for (int nt = 0; nt < 4; ++nt) acc[nt][r] *= inv * w4[nt];
  }
#pragma unroll
  for (int nt = 0; nt < 4; ++nt) scat256(Ko, w * 16, lane, nt * 16 + (lane & 15), acc[nt]);
#pragma unroll
  for (int nt = 0; nt < 4; ++nt) {
    int d = nt * 16 + (lane & 15);
    int tl0 = w * 16 + ((lane >> 4) << 2);
#pragma unroll
    for (int r = 0; r < 4; ++r)
      *(short*)((char*)Vt + swz128(d * 128 + (tl0 + r) * 2)) = f2bf(acc[4 + nt][r]);
  }

  __syncthreads();
  stage64x64(Wd, wb + OFF_KR, 64, tid);
  __syncthreads();
  f4v kr[4];
#pragma unroll
  for (int nt = 0; nt < 4; ++nt) kr[nt] = z4();
#pragma unroll
  for (int ks = 0; ks < 2; ++ks) {
    bf8v a = ldA128(Xs, arow, ks * 32 + koff);
#pragma unroll
    for (int nt = 0; nt < 4; ++nt) {
      bf8v b = ldA128(Wd, nt * 16 + (lane & 15), ks * 32 + koff);
      kr[nt] = MFMA16(a, b, kr[nt]);
    }
  }
#pragma unroll
  for (int nt = 0; nt < 4; ++nt) scat256(Ko, w * 16, lane, 64 + nt * 16 + (lane & 15), kr[nt]);
  __syncthreads();

  short* kdst = kb + ((size_t)bh * T + t0) * 128;
#pragma unroll
  for (int p = 0; p < 4; ++p) {
    int ci = tid + p * 256;
    int r = ci >> 4, c = (ci & 15) << 3;
    *(bf8v*)(kdst + (size_t)r * 128 + c) =
        *(const bf8v*)((const char*)Ko + swz256(ci * 16));
  }
#pragma unroll
  for (int p = 0; p < 2; ++p) {
    int ci = tid + p * 256;
    int d = ci >> 3, c = (ci & 7) << 3;
    *(bf8v*)(vtg + ((size_t)bh * 64 + d) * T + t0 + c) =
        *(const bf8v*)((const char*)Vt + swz128(ci * 16));
  }
}

// ---------------------------------------------------------------------------
// attn v5: 1024 blocks x 128 threads (2 waves). 32-row q-subtiles paired
// (i, 63-i) -> uniform 33 K-tiles/block; 4 blocks/CU (36KB LDS) so other
// blocks cover one block's barrier drain. K double-buffered via
// global_load_lds (L2-resident per XCD-clustered bh); V to regs; softmax
// wave-private: exp2 domain, DPP reductions, defer-max, final-tile-only mask.
// ---------------------------------------------------------------------------
__global__ __launch_bounds__(128) void attn_mfma(
    const short* __restrict__ qb, const short* __restrict__ kb,
    const short* __restrict__ vtg, const short* __restrict__ wb,
    float* __restrict__ out) {
  __shared__ __attribute__((aligned(16))) short Ks[2][64 * 128]; // swz256, 16KB ea
  __shared__ __attribute__((aligned(16))) short Ps[32 * 64];     // swz128, 4KB

  const int tid = threadIdx.x, lane = tid & 63, w = tid >> 6; // w in {0,1}
  const int lin = blockIdx.x;               // [0,1024)
  const int xcd = lin & 7, slot = lin >> 3; // slot [0,128)
  const int bh = xcd + 8 * (slot >> 5);     // 4 bh per XCD -> KV L2-resident
  const int px = slot & 31;
  const int qs_pair[2] = {px, 63 - px};     // 32-row q-subtile indices

  const int b = bh >> 4, h = bh & 15;
  const int koff = (lane >> 4) << 3;
  const int c16 = lane & 15;
  const int rg4 = (lane >> 4) << 2;

  const short* kbh = kb + (size_t)bh * T * 128;
  const short* vbh = vtg + (size_t)bh * 64 * T;

  // stage K-tile jt (64 rows x 256B) into Ks[buf]: linear LDS dest,
  // inverse-swizzled per-lane global src (swz256 is an involution)
  auto stageK = [&](int jt, int buf) {
    const char* src = (const char*)(kbh + jt * 64 * 128);
    char* dst = (char*)&Ks[buf][0];
#pragma unroll
    for (int p = 0; p < 8; ++p) {
      int base = p * 128 + w * 64; // wave-uniform chunk base
      gload_lds16(src + swz256((base + lane) * 16), dst + base * 16);
    }
  };

  int cur = 0;
  stageK(0, 0);
  __syncthreads();

  for (int seg = 0; seg < 2; ++seg) {
    const int qs = qs_pair[seg];
    const int cnt = (qs >> 1) + 1;
    const int t0 = qs * 32;
    const int lrow = w * 16 + rg4; // first of lane's 4 rows within 32-row tile

    // Q fragments: rows t0 + w*16 + c16, full k=128
    bf8v aq[4];
    {
      const short* qsrc = qb + ((size_t)bh * T + t0 + w * 16 + c16) * 128;
#pragma unroll
      for (int ks = 0; ks < 4; ++ks) aq[ks] = *(const bf8v*)(qsrc + ks * 32 + koff);
    }

    f4v ctx[4];
    float m[4], l[4];
#pragma unroll
    for (int nt = 0; nt < 4; ++nt) ctx[nt] = z4();
#pragma unroll
    for (int r = 0; r < 4; ++r) { m[r] = -INFINITY; l[r] = 0.f; }

    for (int j = 0; j < cnt; ++j) {
      const bool finalj = (j == cnt - 1);
      // prefetch next K tile (next j, or seg1's j=0)
      if (!(seg == 1 && finalj)) stageK(finalj ? 0 : j + 1, cur ^ 1);

      const int j0 = j * 64;
      // V fragments for this tile (consumed at PV; latency hides under QK)
      bf8v vb[2][4];
#pragma unroll
      for (int ks = 0; ks < 2; ++ks)
#pragma unroll
        for (int nt = 0; nt < 4; ++nt)
          vb[ks][nt] = *(const bf8v*)(vbh + (size_t)(nt * 16 + c16) * T +
                                      j0 + ks * 32 + koff);

      // QK^T from LDS (q already carries PS*log2e scaling)
      f4v s[4];
#pragma unroll
      for (int nt = 0; nt < 4; ++nt) s[nt] = z4();
#pragma unroll
      for (int ks = 0; ks < 4; ++ks) {
#pragma unroll
        for (int nt = 0; nt < 4; ++nt) {
          bf8v bk = ldA256(Ks[cur], nt * 16 + c16, ks * 32 + koff);
          s[nt] = MFMA16(aq[ks], bk, s[nt]);
        }
      }

      if (finalj) { // causal mask only on the final (diagonal-containing) tile
#pragma unroll
        for (int r = 0; r < 4; ++r) {
          const int grow = t0 + lrow + r;
#pragma unroll
          for (int nt = 0; nt < 4; ++nt)
            if (j0 + nt * 16 + c16 > grow) s[nt][r] = -INFINITY;
        }
      }

      // online softmax, exp2 domain, defer-max (THR=8 -> p bounded by 2^8)
      float mx4[4], need = -1e30f;
#pragma unroll
      for (int r = 0; r < 4; ++r) {
        float mx = rowmax16(fmaxf(fmaxf(s[0][r], s[1][r]), fmaxf(s[2][r], s[3][r])));
        mx4[r] = mx;
        need = fmaxf(need, mx - m[r]);
      }
      if (__any(need > 8.f)) {
#pragma unroll
        for (int r = 0; r < 4; ++r) {
          const float mn  = fmaxf(m[r], mx4[r]);
          const float scl = __builtin_amdgcn_exp2f(m[r] - mn);
          l[r] *= scl;
#pragma unroll
          for (int nt = 0; nt < 4; ++nt) ctx[nt][r] *= scl;
          m[r] = mn;
        }
      }
#pragma unroll
      for (int r = 0; r < 4; ++r) {
        float rs = 0.f, p4[4];
#pragma unroll
        for (int nt = 0; nt < 4; ++nt) {
          p4[nt] = __builtin_amdgcn_exp2f(s[nt][r] - m[r]);
          rs += p4[nt];
        }
        l[r] += rowsum16(rs);
#pragma unroll
        for (int nt = 0; nt < 4; ++nt)
          *(short*)((char*)Ps + swz128((lrow + r) * 128 + (nt * 16 + c16) * 2)) =
              f2bf(p4[nt]);
      }

      // PV: P from wave-private LDS rows (no barrier needed), V from regs
#pragma unroll
      for (int ks = 0; ks < 2; ++ks) {
        bf8v pa = ldA128(Ps, w * 16 + c16, ks * 32 + koff);
#pragma unroll
        for (int nt = 0; nt < 4; ++nt) ctx[nt] = MFMA16(pa, vb[ks][nt], ctx[nt]);
      }

      __syncthreads(); // K dbuf swap (implicit vmcnt(0) drains prefetch)
      cur ^= 1;
    }

    // epilogue: ctx/l -> Ps (wave-private rows), out = ctx @ W_O^T
    f4v cn[4];
#pragma unroll
    for (int nt = 0; nt < 4; ++nt) {
#pragma unroll
      for (int r = 0; r < 4; ++r) cn[nt][r] = ctx[nt][r] / l[r];
    }
#pragma unroll
    for (int nt = 0; nt < 4; ++nt) scat128(Ps, w * 16, lane, nt, cn[nt]);

    f4v o[4];
#pragma unroll
    for (int nt = 0; nt < 4; ++nt) o[nt] = z4();
#pragma unroll
    for (int ks = 0; ks < 2; ++ks) {
      bf8v pa = ldA128(Ps, w * 16 + c16, ks * 32 + koff);
#pragma unroll
      for (int nt = 0; nt < 4; ++nt) {
        bf8v bw = *(const bf8v*)(wb + OFF_O + (size_t)(nt * 16 + c16) * 64 +
                                 ks * 32 + koff);
        o[nt] = MFMA16(pa, bw, o[nt]);
      }
    }

    float* obase = out + (size_t)b * T * 1024 + h * 64;
#pragma unroll
    for (int nt = 0; nt < 4; ++nt) {
#pragma unroll
      for (int r = 0; r < 4; ++r)
        obase[(size_t)(t0 + lrow + r) * 1024 + nt * 16 + c16] = o[nt][r];
    }
  }
}

} // namespace

extern "C" void kernel_launch(void* const* d_in, const int* in_sizes, int n_in,
                              void* d_out, int out_size, void* d_ws, size_t ws_size,
                              hipStream_t stream) {
  (void)in_sizes; (void)n_in; (void)out_size; (void)ws_size;
  const float* x     = (const float*)d_in[0];
  const float* W_DQ  = (const float*)d_in[1];
  const float* W_UQ  = (const float*)d_in[2];
  const float* W_DKV = (const float*)d_in[3];
  const float* W_UKV = (const float*)d_in[4];
  const float* W_QR  = (const float*)d_in[5];
  const float* W_KR  = (const float*)d_in[6];
  const float* W_O   = (const float*)d_in[7];
  const float* qnw   = (const float*)d_in[8];
  const float* knw   = (const float*)d_in[9];
  float* out = (float*)d_out;

  short* ws = (short*)d_ws;
  short* xb  = ws;                          // 4,194,304
  short* qb  = ws + (size_t)4194304;        // 8,388,608
  short* kb  = ws + (size_t)12582912;       // 8,388,608
  short* vtg = ws + (size_t)20971520;       // 4,194,304
  short* wb  = ws + (size_t)25165824;       // 274,432

  cvt_x_kernel<<<4096, 256, 0, stream>>>(x, xb);
  cvt_w_kernel<<<W_TOTAL / 256, 256, 0, stream>>>(W_DQ, W_UQ, W_DKV, W_UKV,
                                                  W_QR, W_KR, W_O, wb);
  dim3 grid(T / 64, 32);
  proj_q_mfma<<<grid, 256, 0, stream>>>(xb, wb, qnw, qb);
  proj_kv_mfma<<<grid, 256, 0, stream>>>(xb, wb, knw, kb, vtg);
  attn_mfma<<<1024, 128, 0, stream>>>(qb, kb, vtg, wb, out);
}

// Round 7
// 173.156 us; speedup vs baseline: 1.5438x; 1.0325x over previous
//
#include <hip/hip_runtime.h>
#include <hip/hip_bf16.h>
#include <math.h>

namespace {

constexpr int T  = 2048;
constexpr int HD = 64;
constexpr float EPS = 1.1920929e-07f;
// SCALE * log2(e), folded into q at proj_q write time -> attn softmax runs in exp2 domain
constexpr float PS = 0.125f * 1.44269504f;

// bf16 weight pool offsets (in elements)
constexpr int OFF_DQ  = 0;       // 512*64
constexpr int OFF_UQ  = 32768;   // 64*512
constexpr int OFF_DKV = 65536;   // 1024*64
constexpr int OFF_UKV = 131072;  // 128*1024
constexpr int OFF_QR  = 262144;  // 64*64
constexpr int OFF_KR  = 266240;  // 64*64
constexpr int OFF_O   = 270336;  // 64*64
constexpr int W_TOTAL = 274432;

typedef __attribute__((ext_vector_type(8))) short bf8v;  // 8 bf16 (4 VGPR)
typedef __attribute__((ext_vector_type(4))) float f4v;   // MFMA C/D

#define MFMA16(a, b, c) __builtin_amdgcn_mfma_f32_16x16x32_bf16((a), (b), (c), 0, 0, 0)

__device__ __forceinline__ short f2bf(float f) {
  union { float f; unsigned u; } v; v.f = f;
  unsigned r = v.u + 0x7FFFu + ((v.u >> 16) & 1u); // RNE
  return (short)(r >> 16);
}

__device__ __forceinline__ f4v z4() { f4v z = {0.f, 0.f, 0.f, 0.f}; return z; }

// XOR swizzles: spread row-strided b128 accesses across banks (m214 pattern)
__device__ __forceinline__ int swz128(int b) { return b ^ (((b >> 7) & 7) << 4); }
__device__ __forceinline__ int swz256(int b) { return b ^ (((b >> 8) & 7) << 4); }

__device__ __forceinline__ bf8v ldA128(const short* lds, int row, int k) {
  return *(const bf8v*)((const char*)lds + swz128(row * 128 + k * 2));
}
__device__ __forceinline__ bf8v ldA256(const short* lds, int row, int k) {
  return *(const bf8v*)((const char*)lds + swz256(row * 256 + k * 2));
}

// stage a row-major 64x64 bf16 tile (src row stride = stride elems) into swizzled LDS
__device__ __forceinline__ void stage64x64(short* lds, const short* src, int stride, int tid) {
#pragma unroll
  for (int p = 0; p < 2; ++p) {
    int ci = tid + p * 256;
    int r = ci >> 3, c = (ci & 7) << 3;
    bf8v v = *(const bf8v*)(src + (size_t)r * stride + c);
    *(bf8v*)((char*)lds + swz128(ci * 16)) = v;
  }
}
__device__ __forceinline__ void stage128x64(short* lds, const short* src, int stride, int tid) {
#pragma unroll
  for (int p = 0; p < 4; ++p) {
    int ci = tid + p * 256;
    int r = ci >> 3, c = (ci & 7) << 3;
    bf8v v = *(const bf8v*)(src + (size_t)r * stride + c);
    *(bf8v*)((char*)lds + swz128(ci * 16)) = v;
  }
}

// scatter a 16x16 D-fragment (col=lane&15, row=(lane>>4)*4+r) as bf16 into LDS
__device__ __forceinline__ void scat128(short* lds, int row0, int lane, int nt, f4v v) {
  int col = nt * 16 + (lane & 15);
  int r0 = row0 + ((lane >> 4) << 2);
#pragma unroll
  for (int r = 0; r < 4; ++r)
    *(short*)((char*)lds + swz128((r0 + r) * 128 + col * 2)) = f2bf(v[r]);
}
__device__ __forceinline__ void scat256(short* lds, int row0, int lane, int col, f4v v) {
  int r0 = row0 + ((lane >> 4) << 2);
#pragma unroll
  for (int r = 0; r < 4; ++r)
    *(short*)((char*)lds + swz256((r0 + r) * 256 + col * 2)) = f2bf(v[r]);
}

// async global->LDS, 16B per lane; LDS dest wave-uniform base + lane*16
__device__ __forceinline__ void gload_lds16(const void* g, void* l) {
  __builtin_amdgcn_global_load_lds(
      (const __attribute__((address_space(1))) void*)g,
      (__attribute__((address_space(3))) void*)l, 16, 0, 0);
}

// ---------------------------------------------------------------------------
// conversions
// ---------------------------------------------------------------------------
__global__ __launch_bounds__(256) void cvt_x_kernel(const float* __restrict__ x,
                                                    short* __restrict__ xb) {
  int i = (blockIdx.x * 256 + threadIdx.x) * 4; // over x linear (B,T,D)
  float4 v = *(const float4*)(x + i);
  int d = i & 1023, t = (i >> 10) & 2047, b = i >> 21;
  int h = d >> 6, dd = d & 63;
  short4 o;
  o.x = f2bf(v.x); o.y = f2bf(v.y); o.z = f2bf(v.z); o.w = f2bf(v.w);
  *(short4*)(xb + ((((size_t)b * 16 + h) * T + t) * 64 + dd)) = o;
}

__global__ __launch_bounds__(256) void cvt_w_kernel(
    const float* __restrict__ W_DQ, const float* __restrict__ W_UQ,
    const float* __restrict__ W_DKV, const float* __restrict__ W_UKV,
    const float* __restrict__ W_QR, const float* __restrict__ W_KR,
    const float* __restrict__ W_O, short* __restrict__ wb) {
  int i = blockIdx.x * 256 + threadIdx.x;
  const float* src; int off;
  if      (i < 32768)  { src = W_DQ;  off = 0; }
  else if (i < 65536)  { src = W_UQ;  off = 32768; }
  else if (i < 131072) { src = W_DKV; off = 65536; }
  else if (i < 262144) { src = W_UKV; off = 131072; }
  else if (i < 266240) { src = W_QR;  off = 262144; }
  else if (i < 270336) { src = W_KR;  off = 266240; }
  else                 { src = W_O;   off = 270336; }
  wb[i] = f2bf(src[i - off]);
}

// ---------------------------------------------------------------------------
// proj_q (unchanged from round 5/6 — PS folded via w4 only)
// ---------------------------------------------------------------------------
__global__ __launch_bounds__(256) void proj_q_mfma(
    const short* __restrict__ xb, const short* __restrict__ wb,
    const float* __restrict__ qnw, short* __restrict__ qb) {
  __shared__ __attribute__((aligned(16))) short Xs[64 * 64];
  __shared__ __attribute__((aligned(16))) short Wd[64 * 64];
  __shared__ __attribute__((aligned(16))) short Wu[64 * 64];
  __shared__ __attribute__((aligned(16))) short Cs[64 * 64];
  __shared__ __attribute__((aligned(16))) short Qr[64 * 64];

  const int tid = threadIdx.x, lane = tid & 63, w = tid >> 6;
  const int bh = blockIdx.y, t0 = blockIdx.x * 64;
  const int arow = w * 16 + (lane & 15);
  const int koff = (lane >> 4) << 3;

  stage64x64(Xs, xb + ((size_t)bh * T + t0) * 64, 64, tid);

  f4v acc[4];
#pragma unroll
  for (int nt = 0; nt < 4; ++nt) acc[nt] = z4();

  for (int lc = 0; lc < 8; ++lc) {
    const int l0 = lc * 64;
    __syncthreads();
    stage64x64(Wd, wb + OFF_DQ + (size_t)l0 * 64, 64, tid);
    stage64x64(Wu, wb + OFF_UQ + l0, 512, tid);
    __syncthreads();
    f4v cc[4];
#pragma unroll
    for (int nt = 0; nt < 4; ++nt) cc[nt] = z4();
#pragma unroll
    for (int ks = 0; ks < 2; ++ks) {
      bf8v a = ldA128(Xs, arow, ks * 32 + koff);
#pragma unroll
      for (int nt = 0; nt < 4; ++nt) {
        bf8v b = ldA128(Wd, nt * 16 + (lane & 15), ks * 32 + koff);
        cc[nt] = MFMA16(a, b, cc[nt]);
      }
    }
#pragma unroll
    for (int nt = 0; nt < 4; ++nt) scat128(Cs, w * 16, lane, nt, cc[nt]);
#pragma unroll
    for (int ks = 0; ks < 2; ++ks) {
      bf8v a = ldA128(Cs, arow, ks * 32 + koff);
#pragma unroll
      for (int nt = 0; nt < 4; ++nt) {
        bf8v b = ldA128(Wu, nt * 16 + (lane & 15), ks * 32 + koff);
        acc[nt] = MFMA16(a, b, acc[nt]);
      }
    }
  }

  float w4[4];
#pragma unroll
  for (int nt = 0; nt < 4; ++nt) w4[nt] = qnw[nt * 16 + (lane & 15)] * PS;
  f4v qn[4];
#pragma unroll
  for (int r = 0; r < 4; ++r) {
    float ss = 0.f;
#pragma unroll
    for (int nt = 0; nt < 4; ++nt) ss += acc[nt][r] * acc[nt][r];
    ss += __shfl_xor(ss, 1, 16); ss += __shfl_xor(ss, 2, 16);
    ss += __shfl_xor(ss, 4, 16); ss += __shfl_xor(ss, 8, 16);
    float inv = rsqrtf(ss * (1.f / 64.f) + EPS); // reference rms; PS lives in w4
#pragma unroll
    for (int nt = 0; nt < 4; ++nt) qn[nt][r] = acc[nt][r] * inv * w4[nt];
  }

  __syncthreads();
#pragma unroll
  for (int nt = 0; nt < 4; ++nt) scat128(Cs, w * 16, lane, nt, qn[nt]);
  stage64x64(Wd, wb + OFF_QR, 64, tid);
  __syncthreads();

  f4v qr[4];
#pragma unroll
  for (int nt = 0; nt < 4; ++nt) qr[nt] = z4();
#pragma unroll
  for (int ks = 0; ks < 2; ++ks) {
    bf8v a = ldA128(Cs, arow, ks * 32 + koff);
#pragma unroll
    for (int nt = 0; nt < 4; ++nt) {
      bf8v b = ldA128(Wd, nt * 16 + (lane & 15), ks * 32 + koff);
      qr[nt] = MFMA16(a, b, qr[nt]);
    }
  }
#pragma unroll
  for (int nt = 0; nt < 4; ++nt) scat128(Qr, w * 16, lane, nt, qr[nt]);
  __syncthreads();

  short* qdst = qb + ((size_t)bh * T + t0) * 128;
#pragma unroll
  for (int p = 0; p < 2; ++p) {
    int ci = tid + p * 256;
    int r = ci >> 3, c = (ci & 7) << 3;
    *(bf8v*)(qdst + (size_t)r * 128 + c) =
        *(const bf8v*)((const char*)Cs + swz128(ci * 16));
    *(bf8v*)(qdst + (size_t)r * 128 + 64 + c) =
        *(const bf8v*)((const char*)Qr + swz128(ci * 16));
  }
}

// ---------------------------------------------------------------------------
// proj_kv (unchanged)
// ---------------------------------------------------------------------------
__global__ __launch_bounds__(256) void proj_kv_mfma(
    const short* __restrict__ xb, const short* __restrict__ wb,
    const float* __restrict__ knw, short* __restrict__ kb, short* __restrict__ vtg) {
  __shared__ __attribute__((aligned(16))) short Xs[64 * 64];
  __shared__ __attribute__((aligned(16))) short Wd[64 * 64];
  __shared__ __attribute__((aligned(16))) short Cs[64 * 64];
  __shared__ __attribute__((aligned(16))) short Wu[128 * 64];
  __shared__ __attribute__((aligned(16))) short Ko[64 * 128];
  __shared__ __attribute__((aligned(16))) short Vt[64 * 64];

  const int tid = threadIdx.x, lane = tid & 63, w = tid >> 6;
  const int bh = blockIdx.y, t0 = blockIdx.x * 64;
  const int arow = w * 16 + (lane & 15);
  const int koff = (lane >> 4) << 3;

  stage64x64(Xs, xb + ((size_t)bh * T + t0) * 64, 64, tid);

  f4v acc[8];
#pragma unroll
  for (int nt = 0; nt < 8; ++nt) acc[nt] = z4();

  for (int lc = 0; lc < 16; ++lc) {
    const int l0 = lc * 64;
    __syncthreads();
    stage64x64(Wd, wb + OFF_DKV + (size_t)l0 * 64, 64, tid);
    stage128x64(Wu, wb + OFF_UKV + l0, 1024, tid);
    __syncthreads();
    f4v cc[4];
#pragma unroll
    for (int nt = 0; nt < 4; ++nt) cc[nt] = z4();
#pragma unroll
    for (int ks = 0; ks < 2; ++ks) {
      bf8v a = ldA128(Xs, arow, ks * 32 + koff);
#pragma unroll
      for (int nt = 0; nt < 4; ++nt) {
        bf8v b = ldA128(Wd, nt * 16 + (lane & 15), ks * 32 + koff);
        cc[nt] = MFMA16(a, b, cc[nt]);
      }
    }
#pragma unroll
    for (int nt = 0; nt < 4; ++nt) scat128(Cs, w * 16, lane, nt, cc[nt]);
#pragma unroll
    for (int ks = 0; ks < 2; ++ks) {
      bf8v a = ldA128(Cs, arow, ks * 32 + koff);
#pragma unroll
      for (int nt = 0; nt < 8; ++nt) {
        bf8v b = ldA128(Wu, nt * 16 + (lane & 15), ks * 32 + koff);
        acc[nt] = MFMA16(a, b, acc[nt]);
      }
    }
  }

  float w4[4];
#pragma unroll
  for (int nt = 0; nt < 4; ++nt) w4[nt] = knw[nt * 16 + (lane & 15)];
#pragma unroll
  for (int r = 0; r < 4; ++r) {
    float ss = 0.f;
#pragma unroll
    for (int nt = 0; nt < 4; ++nt) ss += acc[nt][r] * acc[nt][r];
    ss += __shfl_xor(ss, 1, 16); ss += __shfl_xor(ss, 2, 16);
    ss += __shfl_xor(ss, 4, 16); ss += __shfl_xor(ss, 8, 16);
    float inv = rsqrtf(ss * (1.f / 64.f) + EPS);
#pragma unroll
    for (int nt = 0; nt < 4; ++nt) acc[nt][r] *= inv * w4[nt];
  }
#pragma unroll
  for (int nt = 0; nt < 4; ++nt) scat256(Ko, w * 16, lane, nt * 16 + (lane & 15), acc[nt]);
#pragma unroll
  for (int nt = 0; nt < 4; ++nt) {
    int d = nt * 16 + (lane & 15);
    int tl0 = w * 16 + ((lane >> 4) << 2);
#pragma unroll
    for (int r = 0; r < 4; ++r)
      *(short*)((char*)Vt + swz128(d * 128 + (tl0 + r) * 2)) = f2bf(acc[4 + nt][r]);
  }

  __syncthreads();
  stage64x64(Wd, wb + OFF_KR, 64, tid);
  __syncthreads();
  f4v kr[4];
#pragma unroll
  for (int nt = 0; nt < 4; ++nt) kr[nt] = z4();
#pragma unroll
  for (int ks = 0; ks < 2; ++ks) {
    bf8v a = ldA128(Xs, arow, ks * 32 + koff);
#pragma unroll
    for (int nt = 0; nt < 4; ++nt) {
      bf8v b = ldA128(Wd, nt * 16 + (lane & 15), ks * 32 + koff);
      kr[nt] = MFMA16(a, b, kr[nt]);
    }
  }
#pragma unroll
  for (int nt = 0; nt < 4; ++nt) scat256(Ko, w * 16, lane, 64 + nt * 16 + (lane & 15), kr[nt]);
  __syncthreads();

  short* kdst = kb + ((size_t)bh * T + t0) * 128;
#pragma unroll
  for (int p = 0; p < 4; ++p) {
    int ci = tid + p * 256;
    int r = ci >> 4, c = (ci & 15) << 3;
    *(bf8v*)(kdst + (size_t)r * 128 + c) =
        *(const bf8v*)((const char*)Ko + swz256(ci * 16));
  }
#pragma unroll
  for (int p = 0; p < 2; ++p) {
    int ci = tid + p * 256;
    int d = ci >> 3, c = (ci & 7) << 3;
    *(bf8v*)(vtg + ((size_t)bh * 64 + d) * T + t0 + c) =
        *(const bf8v*)((const char*)Vt + swz128(ci * 16));
  }
}

// ---------------------------------------------------------------------------
// attn v6: round-3 skeleton (512 blocks x 4 waves, 64-row q-tile, pair
// (i,31-i), K dbuf via global_load_lds) + SWAPPED QK^T: s = mfma(K,Q) so each
// lane owns one q-row (c16) with 16 k-positions -> in-lane softmax (tree +
// 2 shfl_xor), P packed with hw cvt_pk and written as 4x ds_write_b64
// (conflict-free) instead of 16x 4-way-conflicted ds_write_b16. l/rescale
// factors cross from softmax-row (c16) to ctx-rows (rg4+r) via 4 shfl.
// ---------------------------------------------------------------------------
__global__ __launch_bounds__(256) void attn_mfma(
    const short* __restrict__ qb, const short* __restrict__ kb,
    const short* __restrict__ vtg, const short* __restrict__ wb,
    float* __restrict__ out) {
  __shared__ __attribute__((aligned(16))) short Ks[2][64 * 128]; // swz256, 16KB ea
  __shared__ __attribute__((aligned(16))) short Ps[64 * 64];     // swz128, 8KB

  const int tid = threadIdx.x, lane = tid & 63, w = tid >> 6;
  const int lin = blockIdx.y * 16 + blockIdx.x; // [0,512)
  const int xcd = lin & 7, slot = lin >> 3;     // slot [0,64)
  const int bh = xcd + 8 * (slot >> 4);         // 4 bh per XCD -> KV L2-resident
  const int px = slot & 15;
  const int qt_pair[2] = {px, 31 - px};

  const int b = bh >> 4, h = bh & 15;
  const int c16 = lane & 15;
  const int g = lane >> 4;
  const int koff = g << 3;
  const int rg4 = g << 2;
  const int lbase = lane & 48; // group bits, for row->lane shfl

  const short* kbh = kb + (size_t)bh * T * 128;
  const short* vbh = vtg + (size_t)bh * 64 * T;

  auto stageK = [&](int jt, int buf) {
    const char* src = (const char*)(kbh + jt * 64 * 128);
    char* dst = (char*)&Ks[buf][0];
#pragma unroll
    for (int p = 0; p < 4; ++p) {
      int base = p * 256 + w * 64; // wave-uniform chunk base
      gload_lds16(src + swz256((base + lane) * 16), dst + base * 16);
    }
  };

  const int NTtot = 33;
  int cur = 0, gcnt = 0;
  stageK(0, 0);
  __syncthreads();

  for (int seg = 0; seg < 2; ++seg) {
    const int qt = qt_pair[seg];
    const int t0 = qt * 64;
    const int lrow = w * 16 + rg4;      // ctx rows (within tile): lrow..lrow+3
    const int qglob = t0 + w * 16 + c16; // softmax row (this lane's q-row)

    bf8v aq[4];
    {
      const short* qsrc = qb + ((size_t)bh * T + t0 + w * 16 + c16) * 128;
#pragma unroll
      for (int ks = 0; ks < 4; ++ks) aq[ks] = *(const bf8v*)(qsrc + ks * 32 + koff);
    }

    f4v ctx[4];
    float m = -INFINITY, l = 0.f;
#pragma unroll
    for (int nt = 0; nt < 4; ++nt) ctx[nt] = z4();

    for (int jt = 0; jt <= qt; ++jt, ++gcnt) {
      if (gcnt + 1 < NTtot) stageK((jt < qt) ? jt + 1 : 0, cur ^ 1);

      const int j0 = jt * 64;
      const bool diag = (jt == qt);

      // V fragments (latency hides under QK)
      bf8v vb[2][4];
#pragma unroll
      for (int ks = 0; ks < 2; ++ks)
#pragma unroll
        for (int nt = 0; nt < 4; ++nt)
          vb[ks][nt] = *(const bf8v*)(vbh + (size_t)(nt * 16 + c16) * T +
                                      j0 + ks * 32 + koff);

      // Swapped QK^T: s = mfma(K, Q) -> s[nt][r] = S[kpos = j0+nt*16+rg4+r][qglob]
      f4v s[4];
#pragma unroll
      for (int nt = 0; nt < 4; ++nt) s[nt] = z4();
#pragma unroll
      for (int ks = 0; ks < 4; ++ks) {
#pragma unroll
        for (int nt = 0; nt < 4; ++nt) {
          bf8v bk = ldA256(Ks[cur], nt * 16 + c16, ks * 32 + koff);
          s[nt] = MFMA16(bk, aq[ks], s[nt]); // A=K, B=Q
        }
      }

      if (diag) { // causal mask only on the diagonal tile
#pragma unroll
        for (int nt = 0; nt < 4; ++nt)
#pragma unroll
          for (int r = 0; r < 4; ++r)
            if (j0 + nt * 16 + rg4 + r > qglob) s[nt][r] = -INFINITY;
      }

      // row max: in-lane tree over 16 + 2 cross-group shfl
      f4v mnt;
#pragma unroll
      for (int r = 0; r < 4; ++r)
        mnt[r] = fmaxf(fmaxf(s[0][r], s[1][r]), fmaxf(s[2][r], s[3][r]));
      float mx = fmaxf(fmaxf(mnt[0], mnt[1]), fmaxf(mnt[2], mnt[3]));
      mx = fmaxf(mx, __shfl_xor(mx, 16));
      mx = fmaxf(mx, __shfl_xor(mx, 32)); // uniform across the 4 lanes of a row

      // defer-max rescale (THR=8 in exp2 domain)
      if (__any(mx - m > 8.f)) {
        const float mn  = fmaxf(m, mx);
        const float scl = __builtin_amdgcn_exp2f(m - mn);
        l *= scl; m = mn;
        float sr[4];
#pragma unroll
        for (int r = 0; r < 4; ++r) sr[r] = __shfl(scl, lbase + rg4 + r);
#pragma unroll
        for (int nt = 0; nt < 4; ++nt)
#pragma unroll
          for (int r = 0; r < 4; ++r) ctx[nt][r] *= sr[r];
      }

      // p = exp2(s - m); row sum in-lane + 2 shfl
#pragma unroll
      for (int nt = 0; nt < 4; ++nt)
#pragma unroll
        for (int r = 0; r < 4; ++r)
          s[nt][r] = __builtin_amdgcn_exp2f(s[nt][r] - m);
      f4v sv = s[0] + s[1] + s[2] + s[3];
      float rs = (sv[0] + sv[1]) + (sv[2] + sv[3]);
      rs += __shfl_xor(rs, 16);
      rs += __shfl_xor(rs, 32);
      l += rs;

      // P -> LDS: 4x ds_write_b64, hw cvt_pk pairs (kpos-contiguous per lane)
      {
        char* prow = (char*)Ps;
        const int rbase = (w * 16 + c16) * 128 + koff; // + nt*32
#pragma unroll
        for (int nt = 0; nt < 4; ++nt) {
          __hip_bfloat162 h0 = __float22bfloat162_rn(make_float2(s[nt][0], s[nt][1]));
          __hip_bfloat162 h1 = __float22bfloat162_rn(make_float2(s[nt][2], s[nt][3]));
          uint2 d;
          d.x = *(unsigned int*)&h0;
          d.y = *(unsigned int*)&h1;
          *(uint2*)(prow + swz128(rbase + nt * 32)) = d;
        }
      }

      // PV: P rows are wave-private (written by this wave) -> no barrier
#pragma unroll
      for (int ks = 0; ks < 2; ++ks) {
        bf8v pa = ldA128(Ps, w * 16 + c16, ks * 32 + koff);
#pragma unroll
        for (int nt = 0; nt < 4; ++nt) ctx[nt] = MFMA16(pa, vb[ks][nt], ctx[nt]);
      }

      __syncthreads(); // K dbuf swap (drains prefetch)
      cur ^= 1;
    }

    // epilogue: ctx rows rg4+r need l of q-row rg4+r (lives at lane c16=rg4+r)
    float linv[4];
#pragma unroll
    for (int r = 0; r < 4; ++r) linv[r] = 1.0f / __shfl(l, lbase + rg4 + r);
    f4v cn[4];
#pragma unroll
    for (int nt = 0; nt < 4; ++nt)
#pragma unroll
      for (int r = 0; r < 4; ++r) cn[nt][r] = ctx[nt][r] * linv[r];
#pragma unroll
    for (int nt = 0; nt < 4; ++nt) scat128(Ps, w * 16, lane, nt, cn[nt]);

    f4v o[4];
#pragma unroll
    for (int nt = 0; nt < 4; ++nt) o[nt] = z4();
#pragma unroll
    for (int ks = 0; ks < 2; ++ks) {
      bf8v pa = ldA128(Ps, w * 16 + c16, ks * 32 + koff);
#pragma unroll
      for (int nt = 0; nt < 4; ++nt) {
        bf8v bw = *(const bf8v*)(wb + OFF_O + (size_t)(nt * 16 + c16) * 64 +
                                 ks * 32 + koff);
        o[nt] = MFMA16(pa, bw, o[nt]);
      }
    }

    float* obase = out + (size_t)b * T * 1024 + h * 64;
#pragma unroll
    for (int nt = 0; nt < 4; ++nt) {
#pragma unroll
      for (int r = 0; r < 4; ++r)
        obase[(size_t)(t0 + lrow + r) * 1024 + nt * 16 + c16] = o[nt][r];
    }
  }
}

} // namespace

extern "C" void kernel_launch(void* const* d_in, const int* in_sizes, int n_in,
                              void* d_out, int out_size, void* d_ws, size_t ws_size,
                              hipStream_t stream) {
  (void)in_sizes; (void)n_in; (void)out_size; (void)ws_size;
  const float* x     = (const float*)d_in[0];
  const float* W_DQ  = (const float*)d_in[1];
  const float* W_UQ  = (const float*)d_in[2];
  const float* W_DKV = (const float*)d_in[3];
  const float* W_UKV = (const float*)d_in[4];
  const float* W_QR  = (const float*)d_in[5];
  const float* W_KR  = (const float*)d_in[6];
  const float* W_O   = (const float*)d_in[7];
  const float* qnw   = (const float*)d_in[8];
  const float* knw   = (const float*)d_in[9];
  float* out = (float*)d_out;

  short* ws = (short*)d_ws;
  short* xb  = ws;                          // 4,194,304
  short* qb  = ws + (size_t)4194304;        // 8,388,608
  short* kb  = ws + (size_t)12582912;       // 8,388,608
  short* vtg = ws + (size_t)20971520;       // 4,194,304
  short* wb  = ws + (size_t)25165824;       // 274,432

  cvt_x_kernel<<<4096, 256, 0, stream>>>(x, xb);
  cvt_w_kernel<<<W_TOTAL / 256, 256, 0, stream>>>(W_DQ, W_UQ, W_DKV, W_UKV,
                                                  W_QR, W_KR, W_O, wb);
  dim3 grid(T / 64, 32);
  proj_q_mfma<<<grid, 256, 0, stream>>>(xb, wb, qnw, qb);
  proj_kv_mfma<<<grid, 256, 0, stream>>>(xb, wb, knw, kb, vtg);
  dim3 agrid(16, 32); // paired q-tiles, uniform work
  attn_mfma<<<agrid, 256, 0, stream>>>(qb, kb, vtg, wb, out);
}

// Round 8
// 149.684 us; speedup vs baseline: 1.7858x; 1.1568x over previous
//
#include <hip/hip_runtime.h>
#include <hip/hip_bf16.h>
#include <math.h>

namespace {

constexpr int T  = 2048;
constexpr int HD = 64;
constexpr float EPS = 1.1920929e-07f;
// SCALE * log2(e), folded into q at proj_q write time -> attn softmax runs in exp2 domain
constexpr float PS = 0.125f * 1.44269504f;

// bf16 weight pool offsets (in elements)
constexpr int OFF_DQ  = 0;       // 512*64
constexpr int OFF_UQ  = 32768;   // 64*512
constexpr int OFF_DKV = 65536;   // 1024*64
constexpr int OFF_UKV = 131072;  // 128*1024
constexpr int OFF_QR  = 262144;  // 64*64
constexpr int OFF_KR  = 266240;  // 64*64
constexpr int OFF_O   = 270336;  // 64*64
constexpr int W_TOTAL = 274432;

typedef __attribute__((ext_vector_type(8))) short bf8v;  // 8 bf16 (4 VGPR)
typedef __attribute__((ext_vector_type(4))) float f4v;   // MFMA C/D

#define MFMA16(a, b, c) __builtin_amdgcn_mfma_f32_16x16x32_bf16((a), (b), (c), 0, 0, 0)

__device__ __forceinline__ short f2bf(float f) {
  union { float f; unsigned u; } v; v.f = f;
  unsigned r = v.u + 0x7FFFu + ((v.u >> 16) & 1u); // RNE
  return (short)(r >> 16);
}

__device__ __forceinline__ f4v z4() { f4v z = {0.f, 0.f, 0.f, 0.f}; return z; }

// XOR swizzles: spread row-strided b128 accesses across banks (m214 pattern)
__device__ __forceinline__ int swz128(int b) { return b ^ (((b >> 7) & 7) << 4); }
__device__ __forceinline__ int swz256(int b) { return b ^ (((b >> 8) & 7) << 4); }

__device__ __forceinline__ bf8v ldA128(const short* lds, int row, int k) {
  return *(const bf8v*)((const char*)lds + swz128(row * 128 + k * 2));
}
__device__ __forceinline__ bf8v ldA256(const short* lds, int row, int k) {
  return *(const bf8v*)((const char*)lds + swz256(row * 256 + k * 2));
}

// stage a row-major 64x64 bf16 tile (src row stride = stride elems) into swizzled LDS
__device__ __forceinline__ void stage64x64(short* lds, const short* src, int stride, int tid) {
#pragma unroll
  for (int p = 0; p < 2; ++p) {
    int ci = tid + p * 256;
    int r = ci >> 3, c = (ci & 7) << 3;
    bf8v v = *(const bf8v*)(src + (size_t)r * stride + c);
    *(bf8v*)((char*)lds + swz128(ci * 16)) = v;
  }
}
__device__ __forceinline__ void stage128x64(short* lds, const short* src, int stride, int tid) {
#pragma unroll
  for (int p = 0; p < 4; ++p) {
    int ci = tid + p * 256;
    int r = ci >> 3, c = (ci & 7) << 3;
    bf8v v = *(const bf8v*)(src + (size_t)r * stride + c);
    *(bf8v*)((char*)lds + swz128(ci * 16)) = v;
  }
}

// scatter a 16x16 D-fragment (col=lane&15, row=(lane>>4)*4+r) as bf16 into LDS
__device__ __forceinline__ void scat128(short* lds, int row0, int lane, int nt, f4v v) {
  int col = nt * 16 + (lane & 15);
  int r0 = row0 + ((lane >> 4) << 2);
#pragma unroll
  for (int r = 0; r < 4; ++r)
    *(short*)((char*)lds + swz128((r0 + r) * 128 + col * 2)) = f2bf(v[r]);
}
__device__ __forceinline__ void scat256(short* lds, int row0, int lane, int col, f4v v) {
  int r0 = row0 + ((lane >> 4) << 2);
#pragma unroll
  for (int r = 0; r < 4; ++r)
    *(short*)((char*)lds + swz256((r0 + r) * 256 + col * 2)) = f2bf(v[r]);
}

// async global->LDS, 16B per lane; LDS dest wave-uniform base + lane*16
__device__ __forceinline__ void gload_lds16(const void* g, void* l) {
  __builtin_amdgcn_global_load_lds(
      (const __attribute__((address_space(1))) void*)g,
      (__attribute__((address_space(3))) void*)l, 16, 0, 0);
}

// ---------------------------------------------------------------------------
// conversions
// ---------------------------------------------------------------------------
__global__ __launch_bounds__(256) void cvt_x_kernel(const float* __restrict__ x,
                                                    short* __restrict__ xb) {
  int i = (blockIdx.x * 256 + threadIdx.x) * 4; // over x linear (B,T,D)
  float4 v = *(const float4*)(x + i);
  int d = i & 1023, t = (i >> 10) & 2047, b = i >> 21;
  int h = d >> 6, dd = d & 63;
  short4 o;
  o.x = f2bf(v.x); o.y = f2bf(v.y); o.z = f2bf(v.z); o.w = f2bf(v.w);
  *(short4*)(xb + ((((size_t)b * 16 + h) * T + t) * 64 + dd)) = o;
}

__global__ __launch_bounds__(256) void cvt_w_kernel(
    const float* __restrict__ W_DQ, const float* __restrict__ W_UQ,
    const float* __restrict__ W_DKV, const float* __restrict__ W_UKV,
    const float* __restrict__ W_QR, const float* __restrict__ W_KR,
    const float* __restrict__ W_O, short* __restrict__ wb) {
  int i = blockIdx.x * 256 + threadIdx.x;
  const float* src; int off;
  if      (i < 32768)  { src = W_DQ;  off = 0; }
  else if (i < 65536)  { src = W_UQ;  off = 32768; }
  else if (i < 131072) { src = W_DKV; off = 65536; }
  else if (i < 262144) { src = W_UKV; off = 131072; }
  else if (i < 266240) { src = W_QR;  off = 262144; }
  else if (i < 270336) { src = W_KR;  off = 266240; }
  else                 { src = W_O;   off = 270336; }
  wb[i] = f2bf(src[i - off]);
}

// ---------------------------------------------------------------------------
// proj_q (unchanged — PS folded via w4 only)
// ---------------------------------------------------------------------------
__global__ __launch_bounds__(256) void proj_q_mfma(
    const short* __restrict__ xb, const short* __restrict__ wb,
    const float* __restrict__ qnw, short* __restrict__ qb) {
  __shared__ __attribute__((aligned(16))) short Xs[64 * 64];
  __shared__ __attribute__((aligned(16))) short Wd[64 * 64];
  __shared__ __attribute__((aligned(16))) short Wu[64 * 64];
  __shared__ __attribute__((aligned(16))) short Cs[64 * 64];
  __shared__ __attribute__((aligned(16))) short Qr[64 * 64];

  const int tid = threadIdx.x, lane = tid & 63, w = tid >> 6;
  const int bh = blockIdx.y, t0 = blockIdx.x * 64;
  const int arow = w * 16 + (lane & 15);
  const int koff = (lane >> 4) << 3;

  stage64x64(Xs, xb + ((size_t)bh * T + t0) * 64, 64, tid);

  f4v acc[4];
#pragma unroll
  for (int nt = 0; nt < 4; ++nt) acc[nt] = z4();

  for (int lc = 0; lc < 8; ++lc) {
    const int l0 = lc * 64;
    __syncthreads();
    stage64x64(Wd, wb + OFF_DQ + (size_t)l0 * 64, 64, tid);
    stage64x64(Wu, wb + OFF_UQ + l0, 512, tid);
    __syncthreads();
    f4v cc[4];
#pragma unroll
    for (int nt = 0; nt < 4; ++nt) cc[nt] = z4();
#pragma unroll
    for (int ks = 0; ks < 2; ++ks) {
      bf8v a = ldA128(Xs, arow, ks * 32 + koff);
#pragma unroll
      for (int nt = 0; nt < 4; ++nt) {
        bf8v b = ldA128(Wd, nt * 16 + (lane & 15), ks * 32 + koff);
        cc[nt] = MFMA16(a, b, cc[nt]);
      }
    }
#pragma unroll
    for (int nt = 0; nt < 4; ++nt) scat128(Cs, w * 16, lane, nt, cc[nt]);
#pragma unroll
    for (int ks = 0; ks < 2; ++ks) {
      bf8v a = ldA128(Cs, arow, ks * 32 + koff);
#pragma unroll
      for (int nt = 0; nt < 4; ++nt) {
        bf8v b = ldA128(Wu, nt * 16 + (lane & 15), ks * 32 + koff);
        acc[nt] = MFMA16(a, b, acc[nt]);
      }
    }
  }

  float w4[4];
#pragma unroll
  for (int nt = 0; nt < 4; ++nt) w4[nt] = qnw[nt * 16 + (lane & 15)] * PS;
  f4v qn[4];
#pragma unroll
  for (int r = 0; r < 4; ++r) {
    float ss = 0.f;
#pragma unroll
    for (int nt = 0; nt < 4; ++nt) ss += acc[nt][r] * acc[nt][r];
    ss += __shfl_xor(ss, 1, 16); ss += __shfl_xor(ss, 2, 16);
    ss += __shfl_xor(ss, 4, 16); ss += __shfl_xor(ss, 8, 16);
    float inv = rsqrtf(ss * (1.f / 64.f) + EPS); // reference rms; PS lives in w4
#pragma unroll
    for (int nt = 0; nt < 4; ++nt) qn[nt][r] = acc[nt][r] * inv * w4[nt];
  }

  __syncthreads();
#pragma unroll
  for (int nt = 0; nt < 4; ++nt) scat128(Cs, w * 16, lane, nt, qn[nt]);
  stage64x64(Wd, wb + OFF_QR, 64, tid);
  __syncthreads();

  f4v qr[4];
#pragma unroll
  for (int nt = 0; nt < 4; ++nt) qr[nt] = z4();
#pragma unroll
  for (int ks = 0; ks < 2; ++ks) {
    bf8v a = ldA128(Cs, arow, ks * 32 + koff);
#pragma unroll
    for (int nt = 0; nt < 4; ++nt) {
      bf8v b = ldA128(Wd, nt * 16 + (lane & 15), ks * 32 + koff);
      qr[nt] = MFMA16(a, b, qr[nt]);
    }
  }
#pragma unroll
  for (int nt = 0; nt < 4; ++nt) scat128(Qr, w * 16, lane, nt, qr[nt]);
  __syncthreads();

  short* qdst = qb + ((size_t)bh * T + t0) * 128;
#pragma unroll
  for (int p = 0; p < 2; ++p) {
    int ci = tid + p * 256;
    int r = ci >> 3, c = (ci & 7) << 3;
    *(bf8v*)(qdst + (size_t)r * 128 + c) =
        *(const bf8v*)((const char*)Cs + swz128(ci * 16));
    *(bf8v*)(qdst + (size_t)r * 128 + 64 + c) =
        *(const bf8v*)((const char*)Qr + swz128(ci * 16));
  }
}

// ---------------------------------------------------------------------------
// proj_kv (unchanged)
// ---------------------------------------------------------------------------
__global__ __launch_bounds__(256) void proj_kv_mfma(
    const short* __restrict__ xb, const short* __restrict__ wb,
    const float* __restrict__ knw, short* __restrict__ kb, short* __restrict__ vtg) {
  __shared__ __attribute__((aligned(16))) short Xs[64 * 64];
  __shared__ __attribute__((aligned(16))) short Wd[64 * 64];
  __shared__ __attribute__((aligned(16))) short Cs[64 * 64];
  __shared__ __attribute__((aligned(16))) short Wu[128 * 64];
  __shared__ __attribute__((aligned(16))) short Ko[64 * 128];
  __shared__ __attribute__((aligned(16))) short Vt[64 * 64];

  const int tid = threadIdx.x, lane = tid & 63, w = tid >> 6;
  const int bh = blockIdx.y, t0 = blockIdx.x * 64;
  const int arow = w * 16 + (lane & 15);
  const int koff = (lane >> 4) << 3;

  stage64x64(Xs, xb + ((size_t)bh * T + t0) * 64, 64, tid);

  f4v acc[8];
#pragma unroll
  for (int nt = 0; nt < 8; ++nt) acc[nt] = z4();

  for (int lc = 0; lc < 16; ++lc) {
    const int l0 = lc * 64;
    __syncthreads();
    stage64x64(Wd, wb + OFF_DKV + (size_t)l0 * 64, 64, tid);
    stage128x64(Wu, wb + OFF_UKV + l0, 1024, tid);
    __syncthreads();
    f4v cc[4];
#pragma unroll
    for (int nt = 0; nt < 4; ++nt) cc[nt] = z4();
#pragma unroll
    for (int ks = 0; ks < 2; ++ks) {
      bf8v a = ldA128(Xs, arow, ks * 32 + koff);
#pragma unroll
      for (int nt = 0; nt < 4; ++nt) {
        bf8v b = ldA128(Wd, nt * 16 + (lane & 15), ks * 32 + koff);
        cc[nt] = MFMA16(a, b, cc[nt]);
      }
    }
#pragma unroll
    for (int nt = 0; nt < 4; ++nt) scat128(Cs, w * 16, lane, nt, cc[nt]);
#pragma unroll
    for (int ks = 0; ks < 2; ++ks) {
      bf8v a = ldA128(Cs, arow, ks * 32 + koff);
#pragma unroll
      for (int nt = 0; nt < 8; ++nt) {
        bf8v b = ldA128(Wu, nt * 16 + (lane & 15), ks * 32 + koff);
        acc[nt] = MFMA16(a, b, acc[nt]);
      }
    }
  }

  float w4[4];
#pragma unroll
  for (int nt = 0; nt < 4; ++nt) w4[nt] = knw[nt * 16 + (lane & 15)];
#pragma unroll
  for (int r = 0; r < 4; ++r) {
    float ss = 0.f;
#pragma unroll
    for (int nt = 0; nt < 4; ++nt) ss += acc[nt][r] * acc[nt][r];
    ss += __shfl_xor(ss, 1, 16); ss += __shfl_xor(ss, 2, 16);
    ss += __shfl_xor(ss, 4, 16); ss += __shfl_xor(ss, 8, 16);
    float inv = rsqrtf(ss * (1.f / 64.f) + EPS);
#pragma unroll
    for (int nt = 0; nt < 4; ++nt) acc[nt][r] *= inv * w4[nt];
  }
#pragma unroll
  for (int nt = 0; nt < 4; ++nt) scat256(Ko, w * 16, lane, nt * 16 + (lane & 15), acc[nt]);
#pragma unroll
  for (int nt = 0; nt < 4; ++nt) {
    int d = nt * 16 + (lane & 15);
    int tl0 = w * 16 + ((lane >> 4) << 2);
#pragma unroll
    for (int r = 0; r < 4; ++r)
      *(short*)((char*)Vt + swz128(d * 128 + (tl0 + r) * 2)) = f2bf(acc[4 + nt][r]);
  }

  __syncthreads();
  stage64x64(Wd, wb + OFF_KR, 64, tid);
  __syncthreads();
  f4v kr[4];
#pragma unroll
  for (int nt = 0; nt < 4; ++nt) kr[nt] = z4();
#pragma unroll
  for (int ks = 0; ks < 2; ++ks) {
    bf8v a = ldA128(Xs, arow, ks * 32 + koff);
#pragma unroll
    for (int nt = 0; nt < 4; ++nt) {
      bf8v b = ldA128(Wd, nt * 16 + (lane & 15), ks * 32 + koff);
      kr[nt] = MFMA16(a, b, kr[nt]);
    }
  }
#pragma unroll
  for (int nt = 0; nt < 4; ++nt) scat256(Ko, w * 16, lane, 64 + nt * 16 + (lane & 15), kr[nt]);
  __syncthreads();

  short* kdst = kb + ((size_t)bh * T + t0) * 128;
#pragma unroll
  for (int p = 0; p < 4; ++p) {
    int ci = tid + p * 256;
    int r = ci >> 4, c = (ci & 15) << 3;
    *(bf8v*)(kdst + (size_t)r * 128 + c) =
        *(const bf8v*)((const char*)Ko + swz256(ci * 16));
  }
#pragma unroll
  for (int p = 0; p < 2; ++p) {
    int ci = tid + p * 256;
    int d = ci >> 3, c = (ci & 7) << 3;
    *(bf8v*)(vtg + ((size_t)bh * 64 + d) * T + t0 + c) =
        *(const bf8v*)((const char*)Vt + swz128(ci * 16));
  }
}

// ---------------------------------------------------------------------------
// attn v7: depth-2 pipeline with counted vmcnt (T3/T4). K: 3 LDS buffers,
// staged 2 tiles ahead (4 gload_lds/wave). V: cooperative LDS staging (kills
// 4x per-wave redundancy), 2 buffers, 1 ahead (2 gload_lds/wave). All loop
// VMEM is global_load_lds; Q (both segs) + W_O preloaded to regs. Per tile:
// issue 6 loads -> QK/softmax -> vmcnt(6) (drains exactly prev tile's 6,
// in-order) -> PV from LDS -> raw s_barrier. Compute = round 7's verified
// swapped-QK softmax. grid (16,32) paired q-tiles, 256 thr, LDS 72KB.
// ---------------------------------------------------------------------------
__global__ __launch_bounds__(256) void attn_mfma(
    const short* __restrict__ qb, const short* __restrict__ kb,
    const short* __restrict__ vtg, const short* __restrict__ wb,
    float* __restrict__ out) {
  __shared__ __attribute__((aligned(16))) short Ks[3][64 * 128]; // swz256, 16KB ea
  __shared__ __attribute__((aligned(16))) short Vs[2][64 * 64];  // swz128, 8KB ea
  __shared__ __attribute__((aligned(16))) short Ps[64 * 64];     // swz128, 8KB

  const int tid = threadIdx.x, lane = tid & 63, w = tid >> 6;
  const int lin = blockIdx.y * 16 + blockIdx.x; // [0,512)
  const int xcd = lin & 7, slot = lin >> 3;     // slot [0,64)
  const int bh = xcd + 8 * (slot >> 4);         // 4 bh per XCD -> KV L2-resident
  const int px = slot & 15;
  const int qtA = px, qtB = 31 - px;
  const int cntA = qtA + 1;
  const int NT = 33;

  const int b = bh >> 4, h = bh & 15;
  const int c16 = lane & 15;
  const int g4 = lane >> 4;
  const int koff = g4 << 3;
  const int rg4 = g4 << 2;
  const int lbase = lane & 48;

  const short* kbh = kb + (size_t)bh * T * 128;
  const short* vbh = vtg + (size_t)bh * 64 * T;

  // preload Q fragments for both segments + W_O fragments (no VMEM in loop)
  bf8v aqA[4], aqB[4], bwo[2][4];
  {
    const short* qA = qb + ((size_t)bh * T + qtA * 64 + w * 16 + c16) * 128;
    const short* qB = qb + ((size_t)bh * T + qtB * 64 + w * 16 + c16) * 128;
#pragma unroll
    for (int ks = 0; ks < 4; ++ks) {
      aqA[ks] = *(const bf8v*)(qA + ks * 32 + koff);
      aqB[ks] = *(const bf8v*)(qB + ks * 32 + koff);
    }
#pragma unroll
    for (int ks = 0; ks < 2; ++ks)
#pragma unroll
      for (int nt = 0; nt < 4; ++nt)
        bwo[ks][nt] = *(const bf8v*)(wb + OFF_O + (size_t)(nt * 16 + c16) * 64 +
                                     ks * 32 + koff);
  }

  // global tile slot gg in [0,33) -> K-tile index
  auto ktile = [&](int gg) { return (gg < NT) ? ((gg < cntA) ? gg : gg - cntA) : 0; };

  auto stageK = [&](int gg) { // 4 gload_lds per wave
    const int jt = ktile(gg);
    const char* src = (const char*)(kbh + jt * 64 * 128); // 16KB contiguous
    char* dst = (char*)&Ks[gg % 3][0];
#pragma unroll
    for (int p = 0; p < 4; ++p) {
      const int base = p * 256 + w * 64;
      gload_lds16(src + swz256((base + lane) * 16), dst + base * 16);
    }
  };
  auto stageV = [&](int gg) { // 2 gload_lds per wave; src rows strided by T
    const int jt = ktile(gg);
    char* dst = (char*)&Vs[gg & 1][0];
#pragma unroll
    for (int p = 0; p < 2; ++p) {
      const int base = p * 256 + w * 64;
      const int tb = swz128((base + lane) * 16); // logical tile byte
      const int r = tb >> 7, cb = tb & 127;
      gload_lds16((const char*)vbh + ((size_t)r * T + jt * 64) * 2 + cb,
                  dst + base * 16);
    }
  };

  // prologue: K(0), K(1), V(0) in flight; drain K(0)+... leave newest 6
  stageK(0);
  stageK(1);
  stageV(0);
  asm volatile("s_waitcnt vmcnt(6)" ::: "memory");
  __builtin_amdgcn_s_barrier();
  __builtin_amdgcn_sched_barrier(0);

  int gg = 0;
  float* obase = out + (size_t)b * T * 1024 + h * 64;

  auto run_seg = [&](const int qt, const bf8v(&aq)[4]) {
    const int t0 = qt * 64;
    const int lrow = w * 16 + rg4;       // ctx rows within tile
    const int qglob = t0 + w * 16 + c16; // this lane's softmax q-row

    f4v ctx[4];
    float m = -INFINITY, l = 0.f;
#pragma unroll
    for (int nt = 0; nt < 4; ++nt) ctx[nt] = z4();

    for (int jt = 0; jt <= qt; ++jt, ++gg) {
      const short* Kb = &Ks[gg % 3][0];
      const short* Vb = &Vs[gg & 1][0];
      // issue next stages first (K 2 ahead, V 1 ahead) — 6 loads/wave
      stageK(gg + 2);
      stageV(gg + 1);

      const int j0 = jt * 64;
      const bool diag = (jt == qt);

      // Swapped QK^T: s = mfma(K, Q) -> s[nt][r] = S[kpos=j0+nt*16+rg4+r][qglob]
      f4v s[4];
#pragma unroll
      for (int nt = 0; nt < 4; ++nt) s[nt] = z4();
#pragma unroll
      for (int ks = 0; ks < 4; ++ks) {
#pragma unroll
        for (int nt = 0; nt < 4; ++nt) {
          bf8v bk = ldA256(Kb, nt * 16 + c16, ks * 32 + koff);
          s[nt] = MFMA16(bk, aq[ks], s[nt]); // A=K, B=Q
        }
      }

      if (diag) {
#pragma unroll
        for (int nt = 0; nt < 4; ++nt)
#pragma unroll
          for (int r = 0; r < 4; ++r)
            if (j0 + nt * 16 + rg4 + r > qglob) s[nt][r] = -INFINITY;
      }

      // row max: in-lane tree + 2 cross-group shfl
      f4v mnt;
#pragma unroll
      for (int r = 0; r < 4; ++r)
        mnt[r] = fmaxf(fmaxf(s[0][r], s[1][r]), fmaxf(s[2][r], s[3][r]));
      float mx = fmaxf(fmaxf(mnt[0], mnt[1]), fmaxf(mnt[2], mnt[3]));
      mx = fmaxf(mx, __shfl_xor(mx, 16));
      mx = fmaxf(mx, __shfl_xor(mx, 32));

      // defer-max rescale (THR=8, exp2 domain)
      if (__any(mx - m > 8.f)) {
        const float mn  = fmaxf(m, mx);
        const float scl = __builtin_amdgcn_exp2f(m - mn);
        l *= scl; m = mn;
        float sr[4];
#pragma unroll
        for (int r = 0; r < 4; ++r) sr[r] = __shfl(scl, lbase + rg4 + r);
#pragma unroll
        for (int nt = 0; nt < 4; ++nt)
#pragma unroll
          for (int r = 0; r < 4; ++r) ctx[nt][r] *= sr[r];
      }

      // p = exp2(s - m); in-lane sum + 2 shfl
#pragma unroll
      for (int nt = 0; nt < 4; ++nt)
#pragma unroll
        for (int r = 0; r < 4; ++r)
          s[nt][r] = __builtin_amdgcn_exp2f(s[nt][r] - m);
      f4v sv = s[0] + s[1] + s[2] + s[3];
      float rs = (sv[0] + sv[1]) + (sv[2] + sv[3]);
      rs += __shfl_xor(rs, 16);
      rs += __shfl_xor(rs, 32);
      l += rs;

      // P -> LDS: 4x ds_write_b64, hw cvt_pk pairs
      {
        char* prow = (char*)Ps;
        const int rbase = (w * 16 + c16) * 128 + koff;
#pragma unroll
        for (int nt = 0; nt < 4; ++nt) {
          __hip_bfloat162 h0 = __float22bfloat162_rn(make_float2(s[nt][0], s[nt][1]));
          __hip_bfloat162 h1 = __float22bfloat162_rn(make_float2(s[nt][2], s[nt][3]));
          uint2 d;
          d.x = *(unsigned int*)&h0;
          d.y = *(unsigned int*)&h1;
          *(uint2*)(prow + swz128(rbase + nt * 32)) = d;
        }
      }

      // counted drain: leaves this tile's 6 loads in flight, completes the
      // previous tile's (K for gg+1, V for gg) — in-order vmcnt semantics
      asm volatile("s_waitcnt vmcnt(6)" ::: "memory");
      __builtin_amdgcn_sched_barrier(0);

      // PV: P wave-private rows; V from LDS (drained above)
#pragma unroll
      for (int ks = 0; ks < 2; ++ks) {
        bf8v pa = ldA128(Ps, w * 16 + c16, ks * 32 + koff);
#pragma unroll
        for (int nt = 0; nt < 4; ++nt) {
          bf8v vf = ldA128(Vb, nt * 16 + c16, ks * 32 + koff);
          ctx[nt] = MFMA16(pa, vf, ctx[nt]);
        }
      }

      __builtin_amdgcn_s_barrier(); // wave sync; no vmem drain needed here
      __builtin_amdgcn_sched_barrier(0);
    }

    // epilogue: ctx rows rg4+r need l of q-row rg4+r (lane c16=rg4+r)
    float linv[4];
#pragma unroll
    for (int r = 0; r < 4; ++r) linv[r] = 1.0f / __shfl(l, lbase + rg4 + r);
    f4v cn[4];
#pragma unroll
    for (int nt = 0; nt < 4; ++nt)
#pragma unroll
      for (int r = 0; r < 4; ++r) cn[nt][r] = ctx[nt][r] * linv[r];
#pragma unroll
    for (int nt = 0; nt < 4; ++nt) scat128(Ps, w * 16, lane, nt, cn[nt]);

    f4v o[4];
#pragma unroll
    for (int nt = 0; nt < 4; ++nt) o[nt] = z4();
#pragma unroll
    for (int ks = 0; ks < 2; ++ks) {
      bf8v pa = ldA128(Ps, w * 16 + c16, ks * 32 + koff);
#pragma unroll
      for (int nt = 0; nt < 4; ++nt) o[nt] = MFMA16(pa, bwo[ks][nt], o[nt]);
    }

#pragma unroll
    for (int nt = 0; nt < 4; ++nt) {
#pragma unroll
      for (int r = 0; r < 4; ++r)
        obase[(size_t)(t0 + lrow + r) * 1024 + nt * 16 + c16] = o[nt][r];
    }
  };

  run_seg(qtA, aqA);
  run_seg(qtB, aqB);
}

} // namespace

extern "C" void kernel_launch(void* const* d_in, const int* in_sizes, int n_in,
                              void* d_out, int out_size, void* d_ws, size_t ws_size,
                              hipStream_t stream) {
  (void)in_sizes; (void)n_in; (void)out_size; (void)ws_size;
  const float* x     = (const float*)d_in[0];
  const float* W_DQ  = (const float*)d_in[1];
  const float* W_UQ  = (const float*)d_in[2];
  const float* W_DKV = (const float*)d_in[3];
  const float* W_UKV = (const float*)d_in[4];
  const float* W_QR  = (const float*)d_in[5];
  const float* W_KR  = (const float*)d_in[6];
  const float* W_O   = (const float*)d_in[7];
  const float* qnw   = (const float*)d_in[8];
  const float* knw   = (const float*)d_in[9];
  float* out = (float*)d_out;

  short* ws = (short*)d_ws;
  short* xb  = ws;                          // 4,194,304
  short* qb  = ws + (size_t)4194304;        // 8,388,608
  short* kb  = ws + (size_t)12582912;       // 8,388,608
  short* vtg = ws + (size_t)20971520;       // 4,194,304
  short* wb  = ws + (size_t)25165824;       // 274,432

  cvt_x_kernel<<<4096, 256, 0, stream>>>(x, xb);
  cvt_w_kernel<<<W_TOTAL / 256, 256, 0, stream>>>(W_DQ, W_UQ, W_DKV, W_UKV,
                                                  W_QR, W_KR, W_O, wb);
  dim3 grid(T / 64, 32);
  proj_q_mfma<<<grid, 256, 0, stream>>>(xb, wb, qnw, qb);
  proj_kv_mfma<<<grid, 256, 0, stream>>>(xb, wb, knw, kb, vtg);
  dim3 agrid(16, 32); // paired q-tiles, uniform work
  attn_mfma<<<agrid, 256, 0, stream>>>(qb, kb, vtg, wb, out);
}

// Round 10
// 132.116 us; speedup vs baseline: 2.0233x; 1.1330x over previous
//
#include <hip/hip_runtime.h>
#include <hip/hip_bf16.h>
#include <math.h>

namespace {

constexpr int T  = 2048;
constexpr int HD = 64;
constexpr float EPS = 1.1920929e-07f;
// SCALE * log2(e), folded into q at proj_q write time -> attn softmax runs in exp2 domain
constexpr float PS = 0.125f * 1.44269504f;

// bf16 weight pool offsets (in elements)
constexpr int OFF_DQ  = 0;       // 512*64
constexpr int OFF_UQ  = 32768;   // 64*512
constexpr int OFF_DKV = 65536;   // 1024*64
constexpr int OFF_UKV = 131072;  // 128*1024
constexpr int OFF_QR  = 262144;  // 64*64
constexpr int OFF_KR  = 266240;  // 64*64
constexpr int OFF_O   = 270336;  // 64*64
constexpr int W_TOTAL = 274432;

typedef __attribute__((ext_vector_type(8))) short bf8v;  // 8 bf16 (4 VGPR)
typedef __attribute__((ext_vector_type(4))) float f4v;   // MFMA C/D

#define MFMA16(a, b, c) __builtin_amdgcn_mfma_f32_16x16x32_bf16((a), (b), (c), 0, 0, 0)

// full-strength barrier for raw s_barrier use: compiler memory fences on both
// sides (raw s_barrier has NO memory semantics at IR level — rule #18 class;
// without the fences the compiler may hoist next-tile global_load_lds above
// the barrier into a buffer other waves still read -> the round-9 race)
#define HARD_BARRIER()                                   \
  do {                                                   \
    asm volatile("" ::: "memory");                       \
    __builtin_amdgcn_s_barrier();                        \
    asm volatile("" ::: "memory");                       \
    __builtin_amdgcn_sched_barrier(0);                   \
  } while (0)

__device__ __forceinline__ short f2bf(float f) {
  union { float f; unsigned u; } v; v.f = f;
  unsigned r = v.u + 0x7FFFu + ((v.u >> 16) & 1u); // RNE
  return (short)(r >> 16);
}

__device__ __forceinline__ f4v z4() { f4v z = {0.f, 0.f, 0.f, 0.f}; return z; }

// XOR swizzles: spread row-strided b128 accesses across banks (m214 pattern)
__device__ __forceinline__ int swz128(int b) { return b ^ (((b >> 7) & 7) << 4); }
__device__ __forceinline__ int swz256(int b) { return b ^ (((b >> 8) & 7) << 4); }

__device__ __forceinline__ bf8v ldA128(const short* lds, int row, int k) {
  return *(const bf8v*)((const char*)lds + swz128(row * 128 + k * 2));
}
__device__ __forceinline__ bf8v ldA256(const short* lds, int row, int k) {
  return *(const bf8v*)((const char*)lds + swz256(row * 256 + k * 2));
}

// scatter a 16x16 D-fragment (col=lane&15, row=(lane>>4)*4+r) as bf16 into LDS
__device__ __forceinline__ void scat128(short* lds, int row0, int lane, int nt, f4v v) {
  int col = nt * 16 + (lane & 15);
  int r0 = row0 + ((lane >> 4) << 2);
#pragma unroll
  for (int r = 0; r < 4; ++r)
    *(short*)((char*)lds + swz128((r0 + r) * 128 + col * 2)) = f2bf(v[r]);
}
__device__ __forceinline__ void scat256(short* lds, int row0, int lane, int col, f4v v) {
  int r0 = row0 + ((lane >> 4) << 2);
#pragma unroll
  for (int r = 0; r < 4; ++r)
    *(short*)((char*)lds + swz256((r0 + r) * 256 + col * 2)) = f2bf(v[r]);
}

// async global->LDS, 16B per lane; LDS dest wave-uniform base + lane*16
__device__ __forceinline__ void gload_lds16(const void* g, void* l) {
  __builtin_amdgcn_global_load_lds(
      (const __attribute__((address_space(1))) void*)g,
      (__attribute__((address_space(3))) void*)l, 16, 0, 0);
}

// ---------------------------------------------------------------------------
// conversions
// ---------------------------------------------------------------------------
__global__ __launch_bounds__(256) void cvt_x_kernel(const float* __restrict__ x,
                                                    short* __restrict__ xb) {
  int i = (blockIdx.x * 256 + threadIdx.x) * 4; // over x linear (B,T,D)
  float4 v = *(const float4*)(x + i);
  int d = i & 1023, t = (i >> 10) & 2047, b = i >> 21;
  int h = d >> 6, dd = d & 63;
  short4 o;
  o.x = f2bf(v.x); o.y = f2bf(v.y); o.z = f2bf(v.z); o.w = f2bf(v.w);
  *(short4*)(xb + ((((size_t)b * 16 + h) * T + t) * 64 + dd)) = o;
}

__global__ __launch_bounds__(256) void cvt_w_kernel(
    const float* __restrict__ W_DQ, const float* __restrict__ W_UQ,
    const float* __restrict__ W_DKV, const float* __restrict__ W_UKV,
    const float* __restrict__ W_QR, const float* __restrict__ W_KR,
    const float* __restrict__ W_O, short* __restrict__ wb) {
  int i = blockIdx.x * 256 + threadIdx.x;
  const float* src; int off;
  if      (i < 32768)  { src = W_DQ;  off = 0; }
  else if (i < 65536)  { src = W_UQ;  off = 32768; }
  else if (i < 131072) { src = W_DKV; off = 65536; }
  else if (i < 262144) { src = W_UKV; off = 131072; }
  else if (i < 266240) { src = W_QR;  off = 262144; }
  else if (i < 270336) { src = W_KR;  off = 266240; }
  else                 { src = W_O;   off = 270336; }
  wb[i] = f2bf(src[i - off]);
}

// ---------------------------------------------------------------------------
// proj_q v2: 128-row tile, gload_lds weight staging, depth-1 dbuf, 1 barrier/lc
// (uses __syncthreads() everywhere -> full fence + vmcnt drain, airtight).
// q[.., 0:64] = PS*rmsnorm(q_c)*qnw ; [64:128] = that @ W_QR^T. LDS 64KB.
// ---------------------------------------------------------------------------
__global__ __launch_bounds__(256) void proj_q_mfma(
    const short* __restrict__ xb, const short* __restrict__ wb,
    const float* __restrict__ qnw, short* __restrict__ qb) {
  __shared__ __attribute__((aligned(16))) short Xs[128 * 64];   // 16KB
  __shared__ __attribute__((aligned(16))) short Wd[2][64 * 64]; // 2x8KB
  __shared__ __attribute__((aligned(16))) short Wu[2][64 * 64]; // 2x8KB
  __shared__ __attribute__((aligned(16))) short Cs[128 * 64];   // 16KB

  const int tid = threadIdx.x, lane = tid & 63, w = tid >> 6;
  const int bh = blockIdx.y, t0 = blockIdx.x * 128;
  const int c16 = lane & 15;
  const int koff = (lane >> 4) << 3;

  auto stageWd = [&](int lc) { // W_DQ rows lc*64.., contiguous 8KB
    const char* src = (const char*)(wb + OFF_DQ + lc * 64 * 64);
    char* dst = (char*)&Wd[lc & 1][0];
#pragma unroll
    for (int p = 0; p < 2; ++p) {
      const int base = p * 256 + w * 64;
      gload_lds16(src + swz128((base + lane) * 16), dst + base * 16);
    }
  };
  auto stageWu = [&](int lc) { // W_UQ[n][lc*64+k], row stride 512 elems
    const char* src = (const char*)(wb + OFF_UQ + lc * 64);
    char* dst = (char*)&Wu[lc & 1][0];
#pragma unroll
    for (int p = 0; p < 2; ++p) {
      const int base = p * 256 + w * 64;
      const int lb = swz128((base + lane) * 16);
      gload_lds16(src + (size_t)(lb >> 7) * 1024 + (lb & 127), dst + base * 16);
    }
  };

  // prologue: X tile (16KB contiguous) + first weight buffers
  {
    const char* src = (const char*)(xb + ((size_t)bh * T + t0) * 64);
#pragma unroll
    for (int p = 0; p < 4; ++p) {
      const int base = p * 256 + w * 64;
      gload_lds16(src + swz128((base + lane) * 16), (char*)Xs + base * 16);
    }
  }
  stageWd(0);
  stageWu(0);
  __syncthreads();

  f4v acc[2][4];
#pragma unroll
  for (int rg = 0; rg < 2; ++rg)
#pragma unroll
    for (int nt = 0; nt < 4; ++nt) acc[rg][nt] = z4();

  for (int lc = 0; lc < 8; ++lc) {
    if (lc < 7) { stageWd(lc + 1); stageWu(lc + 1); }
    else { // prefetch W_QR for the epilogue into Wd[0]
      const char* src = (const char*)(wb + OFF_QR);
      char* dst = (char*)&Wd[0][0];
#pragma unroll
      for (int p = 0; p < 2; ++p) {
        const int base = p * 256 + w * 64;
        gload_lds16(src + swz128((base + lane) * 16), dst + base * 16);
      }
    }
    const short* Wdc = &Wd[lc & 1][0];
    const short* Wuc = &Wu[lc & 1][0];

    f4v cc[2][4];
#pragma unroll
    for (int rg = 0; rg < 2; ++rg)
#pragma unroll
      for (int nt = 0; nt < 4; ++nt) cc[rg][nt] = z4();
#pragma unroll
    for (int rg = 0; rg < 2; ++rg)
#pragma unroll
      for (int ks = 0; ks < 2; ++ks) {
        bf8v a = ldA128(Xs, w * 32 + rg * 16 + c16, ks * 32 + koff);
#pragma unroll
        for (int nt = 0; nt < 4; ++nt) {
          bf8v b = ldA128(Wdc, nt * 16 + c16, ks * 32 + koff);
          cc[rg][nt] = MFMA16(a, b, cc[rg][nt]);
        }
      }
#pragma unroll
    for (int rg = 0; rg < 2; ++rg)
#pragma unroll
      for (int nt = 0; nt < 4; ++nt) scat128(Cs, w * 32 + rg * 16, lane, nt, cc[rg][nt]);
#pragma unroll
    for (int rg = 0; rg < 2; ++rg)
#pragma unroll
      for (int ks = 0; ks < 2; ++ks) {
        bf8v a = ldA128(Cs, w * 32 + rg * 16 + c16, ks * 32 + koff);
#pragma unroll
        for (int nt = 0; nt < 4; ++nt) {
          bf8v b = ldA128(Wuc, nt * 16 + c16, ks * 32 + koff);
          acc[rg][nt] = MFMA16(a, b, acc[rg][nt]);
        }
      }
    __syncthreads(); // drains staged weights for next lc; protects buffer reuse
  }

  // RMS norm (PS folded via w4 only — NOT in inv)
  float w4[4];
#pragma unroll
  for (int nt = 0; nt < 4; ++nt) w4[nt] = qnw[nt * 16 + c16] * PS;
#pragma unroll
  for (int rg = 0; rg < 2; ++rg)
#pragma unroll
    for (int r = 0; r < 4; ++r) {
      float ss = 0.f;
#pragma unroll
      for (int nt = 0; nt < 4; ++nt) ss += acc[rg][nt][r] * acc[rg][nt][r];
      ss += __shfl_xor(ss, 1, 16); ss += __shfl_xor(ss, 2, 16);
      ss += __shfl_xor(ss, 4, 16); ss += __shfl_xor(ss, 8, 16);
      float inv = rsqrtf(ss * (1.f / 64.f) + EPS);
#pragma unroll
      for (int nt = 0; nt < 4; ++nt) acc[rg][nt][r] *= inv * w4[nt];
    }

  // qn -> Cs (wave-private rows); q_r = qn @ W_QR^T (Wd[0], landed at last barrier)
#pragma unroll
  for (int rg = 0; rg < 2; ++rg)
#pragma unroll
    for (int nt = 0; nt < 4; ++nt) scat128(Cs, w * 32 + rg * 16, lane, nt, acc[rg][nt]);

  f4v qr[2][4];
#pragma unroll
  for (int rg = 0; rg < 2; ++rg)
#pragma unroll
    for (int nt = 0; nt < 4; ++nt) qr[rg][nt] = z4();
#pragma unroll
  for (int rg = 0; rg < 2; ++rg)
#pragma unroll
    for (int ks = 0; ks < 2; ++ks) {
      bf8v a = ldA128(Cs, w * 32 + rg * 16 + c16, ks * 32 + koff);
#pragma unroll
      for (int nt = 0; nt < 4; ++nt) {
        bf8v b = ldA128(&Wd[0][0], nt * 16 + c16, ks * 32 + koff);
        qr[rg][nt] = MFMA16(a, b, qr[rg][nt]);
      }
    }
  // qr -> Xs region (free after loop; wave-private rows)
#pragma unroll
  for (int rg = 0; rg < 2; ++rg)
#pragma unroll
    for (int nt = 0; nt < 4; ++nt) scat128(Xs, w * 32 + rg * 16, lane, nt, qr[rg][nt]);
  __syncthreads();

  short* qdst = qb + ((size_t)bh * T + t0) * 128;
#pragma unroll
  for (int p = 0; p < 4; ++p) {
    int ci = tid + p * 256;
    int r = ci >> 3, c = (ci & 7) << 3;
    *(bf8v*)(qdst + (size_t)r * 128 + c) =
        *(const bf8v*)((const char*)Cs + swz128(ci * 16));
    *(bf8v*)(qdst + (size_t)r * 128 + 64 + c) =
        *(const bf8v*)((const char*)Xs + swz128(ci * 16));
  }
}

// ---------------------------------------------------------------------------
// proj_kv v2: 128-row tile, gload_lds staging, depth-1 dbuf, 1 barrier/lc.
// k = [rms(kv[:,:64])*knw, xh W_KR^T]; vt[bh][d][t] = kv[:,64:]^T. LDS 80KB.
// ---------------------------------------------------------------------------
__global__ __launch_bounds__(256) void proj_kv_mfma(
    const short* __restrict__ xb, const short* __restrict__ wb,
    const float* __restrict__ knw, short* __restrict__ kb, short* __restrict__ vtg) {
  __shared__ __attribute__((aligned(16))) short Xs[128 * 64];    // 16KB
  __shared__ __attribute__((aligned(16))) short Wd[2][64 * 64];  // 2x8KB
  __shared__ __attribute__((aligned(16))) short Wu[2][128 * 64]; // 2x16KB (-> Ko 32KB)
  __shared__ __attribute__((aligned(16))) short Cs[128 * 64];    // 16KB (-> Vt)

  const int tid = threadIdx.x, lane = tid & 63, w = tid >> 6;
  const int bh = blockIdx.y, t0 = blockIdx.x * 128;
  const int c16 = lane & 15;
  const int g4 = lane >> 4;
  const int koff = g4 << 3;
  const int rg4 = g4 << 2;

  auto stageWd = [&](int lc) { // W_DKV rows lc*64.., contiguous 8KB
    const char* src = (const char*)(wb + OFF_DKV + lc * 64 * 64);
    char* dst = (char*)&Wd[lc & 1][0];
#pragma unroll
    for (int p = 0; p < 2; ++p) {
      const int base = p * 256 + w * 64;
      gload_lds16(src + swz128((base + lane) * 16), dst + base * 16);
    }
  };
  auto stageWu = [&](int lc) { // W_UKV[n][lc*64+k], n 0..127, row stride 1024 elems
    const char* src = (const char*)(wb + OFF_UKV + lc * 64);
    char* dst = (char*)&Wu[lc & 1][0];
#pragma unroll
    for (int p = 0; p < 4; ++p) {
      const int base = p * 256 + w * 64;
      const int lb = swz128((base + lane) * 16);
      gload_lds16(src + (size_t)(lb >> 7) * 2048 + (lb & 127), dst + base * 16);
    }
  };

  {
    const char* src = (const char*)(xb + ((size_t)bh * T + t0) * 64);
#pragma unroll
    for (int p = 0; p < 4; ++p) {
      const int base = p * 256 + w * 64;
      gload_lds16(src + swz128((base + lane) * 16), (char*)Xs + base * 16);
    }
  }
  stageWd(0);
  stageWu(0);
  __syncthreads();

  f4v acc[2][8];
#pragma unroll
  for (int rg = 0; rg < 2; ++rg)
#pragma unroll
    for (int nt = 0; nt < 8; ++nt) acc[rg][nt] = z4();

  for (int lc = 0; lc < 16; ++lc) {
    if (lc < 15) { stageWd(lc + 1); stageWu(lc + 1); }
    else { // prefetch W_KR into Wd[0] for the epilogue
      const char* src = (const char*)(wb + OFF_KR);
      char* dst = (char*)&Wd[0][0];
#pragma unroll
      for (int p = 0; p < 2; ++p) {
        const int base = p * 256 + w * 64;
        gload_lds16(src + swz128((base + lane) * 16), dst + base * 16);
      }
    }
    const short* Wdc = &Wd[lc & 1][0];
    const short* Wuc = &Wu[lc & 1][0];

    f4v cc[2][4];
#pragma unroll
    for (int rg = 0; rg < 2; ++rg)
#pragma unroll
      for (int nt = 0; nt < 4; ++nt) cc[rg][nt] = z4();
#pragma unroll
    for (int rg = 0; rg < 2; ++rg)
#pragma unroll
      for (int ks = 0; ks < 2; ++ks) {
        bf8v a = ldA128(Xs, w * 32 + rg * 16 + c16, ks * 32 + koff);
#pragma unroll
        for (int nt = 0; nt < 4; ++nt) {
          bf8v b = ldA128(Wdc, nt * 16 + c16, ks * 32 + koff);
          cc[rg][nt] = MFMA16(a, b, cc[rg][nt]);
        }
      }
#pragma unroll
    for (int rg = 0; rg < 2; ++rg)
#pragma unroll
      for (int nt = 0; nt < 4; ++nt) scat128(Cs, w * 32 + rg * 16, lane, nt, cc[rg][nt]);
#pragma unroll
    for (int rg = 0; rg < 2; ++rg)
#pragma unroll
      for (int ks = 0; ks < 2; ++ks) {
        bf8v a = ldA128(Cs, w * 32 + rg * 16 + c16, ks * 32 + koff);
#pragma unroll
        for (int nt = 0; nt < 8; ++nt) {
          bf8v b = ldA128(Wuc, nt * 16 + c16, ks * 32 + koff);
          acc[rg][nt] = MFMA16(a, b, acc[rg][nt]);
        }
      }
    __syncthreads();
  }

  // k_c RMS on acc[rg][0..3]
  float w4[4];
#pragma unroll
  for (int nt = 0; nt < 4; ++nt) w4[nt] = knw[nt * 16 + c16];
#pragma unroll
  for (int rg = 0; rg < 2; ++rg)
#pragma unroll
    for (int r = 0; r < 4; ++r) {
      float ss = 0.f;
#pragma unroll
      for (int nt = 0; nt < 4; ++nt) ss += acc[rg][nt][r] * acc[rg][nt][r];
      ss += __shfl_xor(ss, 1, 16); ss += __shfl_xor(ss, 2, 16);
      ss += __shfl_xor(ss, 4, 16); ss += __shfl_xor(ss, 8, 16);
      float inv = rsqrtf(ss * (1.f / 64.f) + EPS);
#pragma unroll
      for (int nt = 0; nt < 4; ++nt) acc[rg][nt][r] *= inv * w4[nt];
    }

  // Ko = Wu region as [128][128] (256B rows): k_c cols 0..63
  short* Ko = &Wu[0][0];
#pragma unroll
  for (int rg = 0; rg < 2; ++rg)
#pragma unroll
    for (int nt = 0; nt < 4; ++nt)
      scat256(Ko, w * 32 + rg * 16, lane, nt * 16 + c16, acc[rg][nt]);

  // Vt = Cs region as [64 d][128 t] (256B rows): v transposed
#pragma unroll
  for (int rg = 0; rg < 2; ++rg)
#pragma unroll
    for (int nt = 0; nt < 4; ++nt) {
      const int d = nt * 16 + c16;
      const int tc0 = w * 32 + rg * 16 + rg4;
#pragma unroll
      for (int r = 0; r < 4; ++r)
        *(short*)((char*)Cs + swz256(d * 256 + (tc0 + r) * 2)) =
            f2bf(acc[rg][4 + nt][r]);
    }

  // k_r = xh @ W_KR^T (Wd[0] landed at last loop barrier; Xs wave-private rows)
  f4v kr[2][4];
#pragma unroll
  for (int rg = 0; rg < 2; ++rg)
#pragma unroll
    for (int nt = 0; nt < 4; ++nt) kr[rg][nt] = z4();
#pragma unroll
  for (int rg = 0; rg < 2; ++rg)
#pragma unroll
    for (int ks = 0; ks < 2; ++ks) {
      bf8v a = ldA128(Xs, w * 32 + rg * 16 + c16, ks * 32 + koff);
#pragma unroll
      for (int nt = 0; nt < 4; ++nt) {
        bf8v b = ldA128(&Wd[0][0], nt * 16 + c16, ks * 32 + koff);
        kr[rg][nt] = MFMA16(a, b, kr[rg][nt]);
      }
    }
#pragma unroll
  for (int rg = 0; rg < 2; ++rg)
#pragma unroll
    for (int nt = 0; nt < 4; ++nt)
      scat256(Ko, w * 32 + rg * 16, lane, 64 + nt * 16 + c16, kr[rg][nt]);
  __syncthreads();

  short* kdst = kb + ((size_t)bh * T + t0) * 128;
#pragma unroll
  for (int p = 0; p < 8; ++p) {
    int ci = tid + p * 256;
    int r = ci >> 4, c = (ci & 15) << 3;
    *(bf8v*)(kdst + (size_t)r * 128 + c) =
        *(const bf8v*)((const char*)Ko + swz256(ci * 16));
  }
#pragma unroll
  for (int p = 0; p < 4; ++p) {
    int ci = tid + p * 256;
    int d = ci >> 4, c = (ci & 15) << 3;
    *(bf8v*)(vtg + ((size_t)bh * 64 + d) * T + t0 + c) =
        *(const bf8v*)((const char*)Cs + swz256(ci * 16));
  }
}

// ---------------------------------------------------------------------------
// attn v7c: depth-2 counted-vmcnt pipeline; all raw s_barriers now carry
// explicit compiler memory fences (HARD_BARRIER) so gload_lds issues cannot
// be hoisted across them (the round-9 replay race).
// ---------------------------------------------------------------------------
__global__ __launch_bounds__(256) void attn_mfma(
    const short* __restrict__ qb, const short* __restrict__ kb,
    const short* __restrict__ vtg, const short* __restrict__ wb,
    float* __restrict__ out) {
  __shared__ __attribute__((aligned(16))) short Ks[3][64 * 128]; // swz256, 16KB ea
  __shared__ __attribute__((aligned(16))) short Vs[2][64 * 64];  // swz128, 8KB ea
  __shared__ __attribute__((aligned(16))) short Ps[64 * 64];     // swz128, 8KB

  const int tid = threadIdx.x, lane = tid & 63, w = tid >> 6;
  const int lin = blockIdx.y * 16 + blockIdx.x; // [0,512)
  const int xcd = lin & 7, slot = lin >> 3;     // slot [0,64)
  const int bh = xcd + 8 * (slot >> 4);         // 4 bh per XCD -> KV L2-resident
  const int px = slot & 15;
  const int qtA = px, qtB = 31 - px;
  const int cntA = qtA + 1;
  const int NT = 33;

  const int b = bh >> 4, h = bh & 15;
  const int c16 = lane & 15;
  const int g4 = lane >> 4;
  const int koff = g4 << 3;
  const int rg4 = g4 << 2;
  const int lbase = lane & 48;

  const short* kbh = kb + (size_t)bh * T * 128;
  const short* vbh = vtg + (size_t)bh * 64 * T;

  bf8v aqA[4], aqB[4], bwo[2][4];
  {
    const short* qA = qb + ((size_t)bh * T + qtA * 64 + w * 16 + c16) * 128;
    const short* qB = qb + ((size_t)bh * T + qtB * 64 + w * 16 + c16) * 128;
#pragma unroll
    for (int ks = 0; ks < 4; ++ks) {
      aqA[ks] = *(const bf8v*)(qA + ks * 32 + koff);
      aqB[ks] = *(const bf8v*)(qB + ks * 32 + koff);
    }
#pragma unroll
    for (int ks = 0; ks < 2; ++ks)
#pragma unroll
      for (int nt = 0; nt < 4; ++nt)
        bwo[ks][nt] = *(const bf8v*)(wb + OFF_O + (size_t)(nt * 16 + c16) * 64 +
                                     ks * 32 + koff);
  }

  auto ktile = [&](int gg) { return (gg < NT) ? ((gg < cntA) ? gg : gg - cntA) : 0; };

  auto stageK = [&](int gg) { // 4 gload_lds per wave
    const int jt = ktile(gg);
    const char* src = (const char*)(kbh + jt * 64 * 128);
    char* dst = (char*)&Ks[gg % 3][0];
#pragma unroll
    for (int p = 0; p < 4; ++p) {
      const int base = p * 256 + w * 64;
      gload_lds16(src + swz256((base + lane) * 16), dst + base * 16);
    }
  };
  auto stageV = [&](int gg) { // 2 gload_lds per wave
    const int jt = ktile(gg);
    char* dst = (char*)&Vs[gg & 1][0];
#pragma unroll
    for (int p = 0; p < 2; ++p) {
      const int base = p * 256 + w * 64;
      const int tb = swz128((base + lane) * 16);
      const int r = tb >> 7, cb = tb & 127;
      gload_lds16((const char*)vbh + ((size_t)r * T + jt * 64) * 2 + cb,
                  dst + base * 16);
    }
  };

  stageK(0);
  stageK(1);
  stageV(0);
  asm volatile("s_waitcnt vmcnt(6)" ::: "memory");
  HARD_BARRIER();

  int gg = 0;
  float* obase = out + (size_t)b * T * 1024 + h * 64;

  auto run_seg = [&](const int qt, const bf8v(&aq)[4]) {
    const int t0 = qt * 64;
    const int lrow = w * 16 + rg4;
    const int qglob = t0 + w * 16 + c16;

    f4v ctx[4];
    float m = -INFINITY, l = 0.f;
#pragma unroll
    for (int nt = 0; nt < 4; ++nt) ctx[nt] = z4();

    for (int jt = 0; jt <= qt; ++jt, ++gg) {
      const short* Kb = &Ks[gg % 3][0];
      const short* Vb = &Vs[gg & 1][0];
      stageK(gg + 2);
      stageV(gg + 1);

      const int j0 = jt * 64;
      const bool diag = (jt == qt);

      f4v s[4];
#pragma unroll
      for (int nt = 0; nt < 4; ++nt) s[nt] = z4();
#pragma unroll
      for (int ks = 0; ks < 4; ++ks) {
#pragma unroll
        for (int nt = 0; nt < 4; ++nt) {
          bf8v bk = ldA256(Kb, nt * 16 + c16, ks * 32 + koff);
          s[nt] = MFMA16(bk, aq[ks], s[nt]); // A=K, B=Q (swapped)
        }
      }

      if (diag) {
#pragma unroll
        for (int nt = 0; nt < 4; ++nt)
#pragma unroll
          for (int r = 0; r < 4; ++r)
            if (j0 + nt * 16 + rg4 + r > qglob) s[nt][r] = -INFINITY;
      }

      f4v mnt;
#pragma unroll
      for (int r = 0; r < 4; ++r)
        mnt[r] = fmaxf(fmaxf(s[0][r], s[1][r]), fmaxf(s[2][r], s[3][r]));
      float mx = fmaxf(fmaxf(mnt[0], mnt[1]), fmaxf(mnt[2], mnt[3]));
      mx = fmaxf(mx, __shfl_xor(mx, 16));
      mx = fmaxf(mx, __shfl_xor(mx, 32));

      if (__any(mx - m > 8.f)) {
        const float mn  = fmaxf(m, mx);
        const float scl = __builtin_amdgcn_exp2f(m - mn);
        l *= scl; m = mn;
        float sr[4];
#pragma unroll
        for (int r = 0; r < 4; ++r) sr[r] = __shfl(scl, lbase + rg4 + r);
#pragma unroll
        for (int nt = 0; nt < 4; ++nt)
#pragma unroll
          for (int r = 0; r < 4; ++r) ctx[nt][r] *= sr[r];
      }

#pragma unroll
      for (int nt = 0; nt < 4; ++nt)
#pragma unroll
        for (int r = 0; r < 4; ++r)
          s[nt][r] = __builtin_amdgcn_exp2f(s[nt][r] - m);
      f4v sv = s[0] + s[1] + s[2] + s[3];
      float rs = (sv[0] + sv[1]) + (sv[2] + sv[3]);
      rs += __shfl_xor(rs, 16);
      rs += __shfl_xor(rs, 32);
      l += rs;

      {
        char* prow = (char*)Ps;
        const int rbase = (w * 16 + c16) * 128 + koff;
#pragma unroll
        for (int nt = 0; nt < 4; ++nt) {
          __hip_bfloat162 h0 = __float22bfloat162_rn(make_float2(s[nt][0], s[nt][1]));
          __hip_bfloat162 h1 = __float22bfloat162_rn(make_float2(s[nt][2], s[nt][3]));
          uint2 d;
          d.x = *(unsigned int*)&h0;
          d.y = *(unsigned int*)&h1;
          *(uint2*)(prow + swz128(rbase + nt * 32)) = d;
        }
      }

      // drain prev tile's loads (leaves this tile's 6 in flight), then barrier
      // so ALL waves' V(gg) chunks are landed before any PV read
      asm volatile("s_waitcnt vmcnt(6)" ::: "memory");
      HARD_BARRIER();

#pragma unroll
      for (int ks = 0; ks < 2; ++ks) {
        bf8v pa = ldA128(Ps, w * 16 + c16, ks * 32 + koff);
#pragma unroll
        for (int nt = 0; nt < 4; ++nt) {
          bf8v vf = ldA128(Vb, nt * 16 + c16, ks * 32 + koff);
          ctx[nt] = MFMA16(pa, vf, ctx[nt]);
        }
      }

      HARD_BARRIER(); // buffer-reuse WAR fence (reads done before next stages)
    }

    float linv[4];
#pragma unroll
    for (int r = 0; r < 4; ++r) linv[r] = 1.0f / __shfl(l, lbase + rg4 + r);
    f4v cn[4];
#pragma unroll
    for (int nt = 0; nt < 4; ++nt)
#pragma unroll
      for (int r = 0; r < 4; ++r) cn[nt][r] = ctx[nt][r] * linv[r];
#pragma unroll
    for (int nt = 0; nt < 4; ++nt) scat128(Ps, w * 16, lane, nt, cn[nt]);

    f4v o[4];
#pragma unroll
    for (int nt = 0; nt < 4; ++nt) o[nt] = z4();
#pragma unroll
    for (int ks = 0; ks < 2; ++ks) {
      bf8v pa = ldA128(Ps, w * 16 + c16, ks * 32 + koff);
#pragma unroll
      for (int nt = 0; nt < 4; ++nt) o[nt] = MFMA16(pa, bwo[ks][nt], o[nt]);
    }

#pragma unroll
    for (int nt = 0; nt < 4; ++nt) {
#pragma unroll
      for (int r = 0; r < 4; ++r)
        obase[(size_t)(t0 + lrow + r) * 1024 + nt * 16 + c16] = o[nt][r];
    }
  };

  run_seg(qtA, aqA);
  run_seg(qtB, aqB);
}

} // namespace

extern "C" void kernel_launch(void* const* d_in, const int* in_sizes, int n_in,
                              void* d_out, int out_size, void* d_ws, size_t ws_size,
                              hipStream_t stream) {
  (void)in_sizes; (void)n_in; (void)out_size; (void)ws_size;
  const float* x     = (const float*)d_in[0];
  const float* W_DQ  = (const float*)d_in[1];
  const float* W_UQ  = (const float*)d_in[2];
  const float* W_DKV = (const float*)d_in[3];
  const float* W_UKV = (const float*)d_in[4];
  const float* W_QR  = (const float*)d_in[5];
  const float* W_KR  = (const float*)d_in[6];
  const float* W_O   = (const float*)d_in[7];
  const float* qnw   = (const float*)d_in[8];
  const float* knw   = (const float*)d_in[9];
  float* out = (float*)d_out;

  short* ws = (short*)d_ws;
  short* xb  = ws;                          // 4,194,304
  short* qb  = ws + (size_t)4194304;        // 8,388,608
  short* kb  = ws + (size_t)12582912;       // 8,388,608
  short* vtg = ws + (size_t)20971520;       // 4,194,304
  short* wb  = ws + (size_t)25165824;       // 274,432

  cvt_x_kernel<<<4096, 256, 0, stream>>>(x, xb);
  cvt_w_kernel<<<W_TOTAL / 256, 256, 0, stream>>>(W_DQ, W_UQ, W_DKV, W_UKV,
                                                  W_QR, W_KR, W_O, wb);
  dim3 pgrid(T / 128, 32); // 128-row tiles
  proj_q_mfma<<<pgrid, 256, 0, stream>>>(xb, wb, qnw, qb);
  proj_kv_mfma<<<pgrid, 256, 0, stream>>>(xb, wb, knw, kb, vtg);
  dim3 agrid(16, 32); // paired q-tiles, uniform work
  attn_mfma<<<agrid, 256, 0, stream>>>(qb, kb, vtg, wb, out);
}